// Round 11
// baseline (686.150 us; speedup 1.0000x reference)
//
#include <hip/hip_runtime.h>
#include <hip/hip_bf16.h>
#include <hip/hip_cooperative_groups.h>
#include <stdint.h>

namespace cg = cooperative_groups;

#define NB 16
#define NPT 2048
#define NS 512
#define NK 32
#define PTOT (NB*NS*NK)   // 262144 positions
#define EPSV 1e-5f

typedef __attribute__((ext_vector_type(8))) short short8;
typedef __attribute__((ext_vector_type(4))) float floatx4;

// ws layout (float indices)
#define WS_NEWXYZ 0            // 24576
// ST: L1 sum 2x64@0 sq@128 | L2 sum 2x64@256 sq@384 | L3 sum 8x128@512 sq 8x128@1536 -> 2560
#define WS_ST     24576        // -> 27136
#define WS_W1BF   27136        // 4096 bf16 -> 29184
#define WS_W2BF   29184        // 8192 bf16 -> 33280
#define WS_W0R    33280        // 64x96 bf16 = 3072 fl -> 36352
#define WS_RAWMAX 36352        // 1048576 bf16 -> 560640
#define WS_PTS_TB 560640       // B*N*64 bf16 -> 1609216
#define WS_Y1     1609216      // 64*PTOT bf16 = 8388608 fl -> 9997824
#define WS_Y2     9997824      // -> 18386432  (~74MB)

__device__ __forceinline__ float bf2f(ushort u){ return __uint_as_float((uint32_t)u<<16); }
__device__ __forceinline__ ushort f2bf(float f){
  uint32_t u = __float_as_uint(f);
  return (ushort)((u + 0x7FFFu + ((u>>16)&1u)) >> 16);
}

template<int CTRL>
__device__ __forceinline__ double dppmax64f(double k){
  long long b = __double_as_longlong(k);
  int lo = (int)(uint32_t)b, hi = (int)(b>>32);
  int olo = __builtin_amdgcn_update_dpp(lo, lo, CTRL, 0xF, 0xF, false);
  int ohi = __builtin_amdgcn_update_dpp(hi, hi, CTRL, 0xF, 0xF, false);
  double o = __hiloint2double(ohi, olo);
  return fmax(o, k);
}
__device__ __forceinline__ unsigned long long u64max(unsigned long long a, unsigned long long b){ return a>b?a:b; }

__device__ __forceinline__ void stats64_phase(const ushort* __restrict__ y, float* __restrict__ stbase,
                                              char* smraw, int blk, int G, int tid)
{
  const int wid = tid>>6, lane = tid&63;
  const int oct = lane & 7, pr = lane >> 3;
  float* sd = (float*)smraw;   // [4][128]
  for (int u = blk; u < 256; u += G){
    __syncthreads();
    const int p0 = u*1024 + wid*256;
    float s[8], s2[8];
    #pragma unroll
    for (int j=0;j<8;j++){ s[j]=0.f; s2[j]=0.f; }
    for (int it=0; it<32; it++){
      int p = p0 + it*8 + pr;
      short8 v = *(const short8*)(y + (size_t)p*64 + oct*8);
      #pragma unroll
      for (int j=0;j<8;j++){
        float f = bf2f((ushort)v[j]);
        s[j] += f; s2[j] = fmaf(f,f,s2[j]);
      }
    }
    #pragma unroll
    for (int off=8; off<64; off<<=1){
      #pragma unroll
      for (int j=0;j<8;j++){ s[j] += __shfl_xor(s[j],off,64); s2[j] += __shfl_xor(s2[j],off,64); }
    }
    if (pr==0){
      #pragma unroll
      for (int j=0;j<8;j++){ sd[wid*128 + oct*8+j] = s[j]; sd[wid*128 + 64+oct*8+j] = s2[j]; }
    }
    __syncthreads();
    if (tid < 128){
      float v = sd[tid]+sd[128+tid]+sd[256+tid]+sd[384+tid];
      int rep = u & 1;
      float* dst = (tid<64) ? (stbase + rep*64 + tid) : (stbase + 128 + rep*64 + (tid-64));
      atomicAdd(dst, v);
    }
  }
}

// ================= single cooperative kernel =================
__global__ __launch_bounds__(256) void mega_kernel(
    const float* __restrict__ xyz, const float* __restrict__ pts,
    const float* __restrict__ w0, const float* __restrict__ b0,
    const float* __restrict__ g0v, const float* __restrict__ bt0,
    const float* __restrict__ w1, const float* __restrict__ b1,
    const float* __restrict__ g1v, const float* __restrict__ bt1,
    const float* __restrict__ w2, const float* __restrict__ b2,
    const float* __restrict__ g2v, const float* __restrict__ bt2,
    float* __restrict__ out, float* __restrict__ ws)
{
  __shared__ __align__(16) char smraw[34944];
  cg::grid_group gridg = cg::this_grid();
  const int blk = blockIdx.x, tid = threadIdx.x;
  const int lane = tid & 63, wid = tid >> 6;
  const int G = (int)gridDim.x;

  float* nxyz = ws + WS_NEWXYZ;
  float* st   = ws + WS_ST;
  ushort* w1b = (ushort*)(ws + WS_W1BF);
  ushort* w2b = (ushort*)(ws + WS_W2BF);
  ushort* w0r = (ushort*)(ws + WS_W0R);
  ushort* rawmax = (ushort*)(ws + WS_RAWMAX);
  ushort* pts_tb = (ushort*)(ws + WS_PTS_TB);
  ushort* y1 = (ushort*)(ws + WS_Y1);
  ushort* y2 = (ushort*)(ws + WS_Y2);

  // ---------------- phase 0: FPS / transpose / weight prep ----------------
  if (blk < 16){
    float4* lc = (float4*)smraw;                 // 2048 x 16B
    double* warr = (double*)(smraw + 32768);     // [2][4]
    int* sel = (int*)(smraw + 32832);            // 512
    const int b = blk;
    const float* xb = xyz + (size_t)b*3*NPT;
    float px[8], py[8], pz[8], dist[8];
    uint32_t lo_[8];
    #pragma unroll
    for (int j=0;j<8;j++){
      int n = j*256 + tid;
      float x = xb[n], y = xb[NPT+n], z = xb[2*NPT+n];
      lc[n] = make_float4(x,y,z,0.f);
      px[j]=x; py[j]=y; pz[j]=z; dist[j]=1e10f;
      lo_[j] = ~(uint32_t)n;
    }
    if (tid==0) sel[0]=0;
    __syncthreads();
    float4 c0 = lc[0];
    float cx = c0.x, cy = c0.y, cz = c0.z;
    for (int t=1;t<NS;t++){
      double kk[8];
      #pragma unroll
      for (int j=0;j<8;j++){
        float dx = __fsub_rn(px[j], cx);
        float dy = __fsub_rn(py[j], cy);
        float dz = __fsub_rn(pz[j], cz);
        float d  = __fadd_rn(__fadd_rn(__fmul_rn(dx,dx),__fmul_rn(dy,dy)),__fmul_rn(dz,dz));
        float dd = fminf(dist[j], d);
        dist[j] = dd;
        kk[j] = __hiloint2double((int)__float_as_uint(dd), (int)lo_[j]);
      }
      double m0 = fmax(kk[0],kk[1]), m1 = fmax(kk[2],kk[3]);
      double m2 = fmax(kk[4],kk[5]), m3 = fmax(kk[6],kk[7]);
      double best = fmax(fmax(m0,m1), fmax(m2,m3));
      best = dppmax64f<0xB1>(best);
      best = dppmax64f<0x4E>(best);
      best = dppmax64f<0x124>(best);
      best = dppmax64f<0x128>(best);
      long long bb = __double_as_longlong(best);
      int bl = (int)(uint32_t)bb, bh = (int)(bb>>32);
      unsigned long long k0 = (((unsigned long long)(uint32_t)__builtin_amdgcn_readlane(bh, 0))<<32)  | (uint32_t)__builtin_amdgcn_readlane(bl, 0);
      unsigned long long k1 = (((unsigned long long)(uint32_t)__builtin_amdgcn_readlane(bh, 16))<<32) | (uint32_t)__builtin_amdgcn_readlane(bl, 16);
      unsigned long long k2 = (((unsigned long long)(uint32_t)__builtin_amdgcn_readlane(bh, 32))<<32) | (uint32_t)__builtin_amdgcn_readlane(bl, 32);
      unsigned long long k3 = (((unsigned long long)(uint32_t)__builtin_amdgcn_readlane(bh, 48))<<32) | (uint32_t)__builtin_amdgcn_readlane(bl, 48);
      unsigned long long kw = u64max(u64max(k0,k1), u64max(k2,k3));
      if (lane==0) warr[(t&1)*4 + wid] = __longlong_as_double((long long)kw);
      __syncthreads();
      double w0_ = warr[(t&1)*4+0], w1_ = warr[(t&1)*4+1], w2_ = warr[(t&1)*4+2], w3_ = warr[(t&1)*4+3];
      double f = fmax(fmax(w0_,w1_), fmax(w2_,w3_));
      int n = (int)(~(uint32_t)__double_as_longlong(f));
      float4 cc = lc[n];
      cx = cc.x; cy = cc.y; cz = cc.z;
      if (tid==0) sel[t]=n;
    }
    __syncthreads();
    for (int s = tid; s < NS; s += 256){
      int n = sel[s];
      float4 cc = lc[n];
      float* np_ = nxyz + ((size_t)b*NS + s)*3;
      np_[0]=cc.x; np_[1]=cc.y; np_[2]=cc.z;
      float* ob = out + (size_t)b*3*NS + s;
      ob[0]=cc.x; ob[NS]=cc.y; ob[2*NS]=cc.z;
    }
  } else {
    float (*tile)[65] = (float(*)[65])smraw;
    for (int u = blk-16; u < 513; u += G-16){
      __syncthreads();
      if (u < 512){
        const int b = u >> 5;
        const int n0 = (u & 31) * 64;
        const int row4 = tid >> 6;
        const float* src = pts + (size_t)b*64*NPT;
        #pragma unroll
        for (int r=0; r<16; r++){
          int cc = r*4 + row4;
          tile[cc][lane] = src[(size_t)cc*NPT + n0 + lane];
        }
        __syncthreads();
        ushort* dst = pts_tb + ((size_t)b*NPT + n0)*64;
        #pragma unroll
        for (int r=0; r<16; r++){
          int nn2 = r*4 + row4;
          dst[(size_t)nn2*64 + lane] = f2bf(tile[lane][nn2]);
        }
      } else {
        for (int i = tid; i < 4096; i += 256) w1b[i] = f2bf(w1[i]);
        for (int i = tid; i < 8192; i += 256) w2b[i] = f2bf(w2[i]);
        for (int i = tid; i < 2560; i += 256) st[i] = 0.f;
        // w0 reorder: col 0-63 = pts weights (w0 col 3..66), 64-66 = xyz weights, 67-95 = 0
        for (int i = tid; i < 6144; i += 256){
          int o = i / 96, k = i - o*96;
          float v = (k < 64) ? w0[o*67 + 3 + k] : ((k < 67) ? w0[o*67 + (k-64)] : 0.f);
          w0r[i] = f2bf(v);
        }
      }
    }
  }
  gridg.sync();

  // ---------------- phase 1: conv1 = ballq + MFMA 96->64 (per-wave group) ----------------
  {
    int* gqrow = (int*)smraw + wid*32;
    const int q = lane>>4, nn = lane&15;
    for (int g = blk*4 + wid; g < NB*NS; g += G*4){
      const int b = g >> 9;
      const float* xb = xyz + (size_t)b*3*NPT;
      const float* cgp = nxyz + (size_t)g*3;
      const float cx = cgp[0], cy = cgp[1], cz = cgp[2];
      {
        const float r2 = 0.2f*0.2f;
        int cnt = 0, first = 0;
        for (int ch=0; ch<NPT/64 && cnt<NK; ch++){
          int n = ch*64 + lane;
          float dx = __fsub_rn(cx, xb[n]);
          float dy = __fsub_rn(cy, xb[NPT+n]);
          float dz = __fsub_rn(cz, xb[2*NPT+n]);
          float d  = __fadd_rn(__fadd_rn(__fmul_rn(dx,dx),__fmul_rn(dy,dy)),__fmul_rn(dz,dz));
          bool in = (d <= r2);
          unsigned long long mask = __ballot(in);
          if (mask){
            if (cnt==0) first = ch*64 + (__ffsll((unsigned long long)mask)-1);
            if (in){
              int pos = cnt + __popcll(mask & ((1ull<<lane)-1ull));
              if (pos < NK) gqrow[pos] = n;
            }
            cnt += __popcll(mask);
          }
        }
        if (cnt < NK && lane >= cnt && lane < NK) gqrow[lane] = first;
      }
      int n0 = gqrow[nn], n1 = gqrow[16+nn];
      float dx0 = xb[n0]-cx, dy0 = xb[NPT+n0]-cy, dz0 = xb[2*NPT+n0]-cz;
      float dx1 = xb[n1]-cx, dy1 = xb[NPT+n1]-cy, dz1 = xb[2*NPT+n1]-cz;
      floatx4 z4 = {0.f,0.f,0.f,0.f};
      floatx4 acc[4][2];
      #pragma unroll
      for (int mt=0;mt<4;mt++){ acc[mt][0]=z4; acc[mt][1]=z4; }
      const ushort* pr0 = pts_tb + ((size_t)b*NPT + n0)*64;
      const ushort* pr1 = pts_tb + ((size_t)b*NPT + n1)*64;
      #pragma unroll
      for (int kh=0; kh<2; kh++){
        short8 B0 = *(const short8*)(pr0 + kh*32 + q*8);
        short8 B1 = *(const short8*)(pr1 + kh*32 + q*8);
        #pragma unroll
        for (int mt=0; mt<4; mt++){
          short8 A = *(const short8*)(w0r + (mt*16+nn)*96 + kh*32 + q*8);
          acc[mt][0] = __builtin_amdgcn_mfma_f32_16x16x32_bf16(A, B0, acc[mt][0], 0,0,0);
          acc[mt][1] = __builtin_amdgcn_mfma_f32_16x16x32_bf16(A, B1, acc[mt][1], 0,0,0);
        }
      }
      {
        short8 B0 = {0,0,0,0,0,0,0,0}, B1 = {0,0,0,0,0,0,0,0};
        if (q==0){
          B0[0]=(short)f2bf(dx0); B0[1]=(short)f2bf(dy0); B0[2]=(short)f2bf(dz0);
          B1[0]=(short)f2bf(dx1); B1[1]=(short)f2bf(dy1); B1[2]=(short)f2bf(dz1);
        }
        #pragma unroll
        for (int mt=0; mt<4; mt++){
          short8 A = *(const short8*)(w0r + (mt*16+nn)*96 + 64 + q*8);
          acc[mt][0] = __builtin_amdgcn_mfma_f32_16x16x32_bf16(A, B0, acc[mt][0], 0,0,0);
          acc[mt][1] = __builtin_amdgcn_mfma_f32_16x16x32_bf16(A, B1, acc[mt][1], 0,0,0);
        }
      }
      #pragma unroll
      for (int nt=0; nt<2; nt++){
        int p = g*32 + nt*16 + nn;
        #pragma unroll
        for (int mt=0; mt<4; mt++){
          float v0 = acc[mt][nt][0] + b0[mt*16 + q*4 + 0];
          float v1 = acc[mt][nt][1] + b0[mt*16 + q*4 + 1];
          float v2 = acc[mt][nt][2] + b0[mt*16 + q*4 + 2];
          float v3 = acc[mt][nt][3] + b0[mt*16 + q*4 + 3];
          uint2 wv;
          wv.x = (uint32_t)f2bf(v0) | ((uint32_t)f2bf(v1)<<16);
          wv.y = (uint32_t)f2bf(v2) | ((uint32_t)f2bf(v3)<<16);
          *(uint2*)(y1 + (size_t)p*64 + mt*16 + q*4) = wv;
        }
      }
    }
  }
  gridg.sync();

  // ---------------- phase 2: stats(y1) -> st[0..256) ----------------
  stats64_phase(y1, st, smraw, blk, G, tid);
  gridg.sync();

  // ---------------- phase 3: conv2 MFMA 64->64 ----------------
  {
    float* aAl = (float*)smraw;
    float* aBl = (float*)(smraw + 256);
    if (tid < 64){
      float s = st[tid] + st[64+tid];
      float qv = st[128+tid] + st[192+tid];
      float mean = s * (1.f/PTOT);
      float var  = qv * (1.f/PTOT) - mean*mean;
      float a = g0v[tid] * rsqrtf(var + EPSV);
      aAl[tid] = a;
      aBl[tid] = fmaf(-mean, a, bt0[tid]);
    }
    __syncthreads();
    const int q = lane>>4, nn = lane&15;
    float a_[2][8], b_[2][8];
    #pragma unroll
    for (int kh=0;kh<2;kh++)
      #pragma unroll
      for (int j=0;j<8;j++){
        a_[kh][j] = aAl[kh*32 + q*8 + j];
        b_[kh][j] = aBl[kh*32 + q*8 + j];
      }
    short8 Af[4][2];
    #pragma unroll
    for (int mt=0;mt<4;mt++)
      #pragma unroll
      for (int kh=0;kh<2;kh++)
        Af[mt][kh] = *(const short8*)(w1b + (mt*16 + nn)*64 + kh*32 + q*8);
    float bias_[4][4];
    #pragma unroll
    for (int mt=0;mt<4;mt++)
      #pragma unroll
      for (int r=0;r<4;r++) bias_[mt][r] = b1[mt*16 + q*4 + r];
    for (int u = blk; u < 2048; u += G){
      const int p0 = (u*4 + wid) * 32;
      floatx4 z4 = {0.f,0.f,0.f,0.f};
      floatx4 acc[4][2];
      #pragma unroll
      for (int mt=0;mt<4;mt++){ acc[mt][0]=z4; acc[mt][1]=z4; }
      #pragma unroll
      for (int nt=0;nt<2;nt++){
        #pragma unroll
        for (int kh=0;kh<2;kh++){
          short8 raw = *(const short8*)(y1 + (size_t)(p0 + nt*16 + nn)*64 + kh*32 + q*8);
          short8 bf;
          #pragma unroll
          for (int j=0;j<8;j++){
            float f = bf2f((ushort)raw[j]);
            f = fmaxf(fmaf(f, a_[kh][j], b_[kh][j]), 0.f);
            bf[j] = (short)f2bf(f);
          }
          #pragma unroll
          for (int mt=0;mt<4;mt++)
            acc[mt][nt] = __builtin_amdgcn_mfma_f32_16x16x32_bf16(Af[mt][kh], bf, acc[mt][nt], 0,0,0);
        }
      }
      #pragma unroll
      for (int nt=0;nt<2;nt++){
        int p = p0 + nt*16 + nn;
        #pragma unroll
        for (int mt=0;mt<4;mt++){
          float v0 = acc[mt][nt][0] + bias_[mt][0];
          float v1 = acc[mt][nt][1] + bias_[mt][1];
          float v2 = acc[mt][nt][2] + bias_[mt][2];
          float v3 = acc[mt][nt][3] + bias_[mt][3];
          uint2 wv;
          wv.x = (uint32_t)f2bf(v0) | ((uint32_t)f2bf(v1)<<16);
          wv.y = (uint32_t)f2bf(v2) | ((uint32_t)f2bf(v3)<<16);
          *(uint2*)(y2 + (size_t)p*64 + mt*16 + q*4) = wv;
        }
      }
    }
  }
  gridg.sync();

  // ---------------- phase 4: stats(y2) -> st[256..512) ----------------
  stats64_phase(y2, st + 256, smraw, blk, G, tid);
  gridg.sync();

  // ---------------- phase 5: conv3 MFMA 64->128, LDS tile, rawmax + L3 stats ----------------
  {
    ushort* tile = (ushort*)smraw;                 // 64 x pitch 132
    float* aAl = (float*)(smraw + 16896);
    float* aBl = (float*)(smraw + 17152);
    if (tid < 64){
      float s = st[256+tid] + st[320+tid];
      float qv = st[384+tid] + st[448+tid];
      float mean = s * (1.f/PTOT);
      float var  = qv * (1.f/PTOT) - mean*mean;
      float a = g1v[tid] * rsqrtf(var + EPSV);
      aAl[tid] = a;
      aBl[tid] = fmaf(-mean, a, bt1[tid]);
    }
    __syncthreads();
    const int q = lane>>4, nn = lane&15;
    float a_[2][8], b_[2][8];
    #pragma unroll
    for (int kh=0;kh<2;kh++)
      #pragma unroll
      for (int j=0;j<8;j++){
        a_[kh][j] = aAl[kh*32 + q*8 + j];
        b_[kh][j] = aBl[kh*32 + q*8 + j];
      }
    for (int u = blk; u < 4096; u += G){
      __syncthreads();
      const int p0 = (u*4 + wid) * 16;
      short8 bfr[2];
      #pragma unroll
      for (int kh=0;kh<2;kh++){
        short8 raw = *(const short8*)(y2 + (size_t)(p0 + nn)*64 + kh*32 + q*8);
        short8 bf;
        #pragma unroll
        for (int j=0;j<8;j++){
          float f = bf2f((ushort)raw[j]);
          f = fmaxf(fmaf(f, a_[kh][j], b_[kh][j]), 0.f);
          bf[j] = (short)f2bf(f);
        }
        bfr[kh] = bf;
      }
      #pragma unroll 1
      for (int mh=0;mh<2;mh++){
        floatx4 z4 = {0.f,0.f,0.f,0.f};
        floatx4 acc[4];
        short8 Af[4][2];
        #pragma unroll
        for (int mt=0;mt<4;mt++){
          acc[mt]=z4;
          #pragma unroll
          for (int kh=0;kh<2;kh++)
            Af[mt][kh] = *(const short8*)(w2b + ((mh*4+mt)*16 + nn)*64 + kh*32 + q*8);
        }
        #pragma unroll
        for (int kh=0;kh<2;kh++)
          #pragma unroll
          for (int mt=0;mt<4;mt++)
            acc[mt] = __builtin_amdgcn_mfma_f32_16x16x32_bf16(Af[mt][kh], bfr[kh], acc[mt], 0,0,0);
        #pragma unroll
        for (int mt=0;mt<4;mt++){
          int m0 = (mh*4+mt)*16;
          float v0 = acc[mt][0] + b2[m0 + q*4 + 0];
          float v1 = acc[mt][1] + b2[m0 + q*4 + 1];
          float v2 = acc[mt][2] + b2[m0 + q*4 + 2];
          float v3 = acc[mt][3] + b2[m0 + q*4 + 3];
          uint2 wv;
          wv.x = (uint32_t)f2bf(v0) | ((uint32_t)f2bf(v1)<<16);
          wv.y = (uint32_t)f2bf(v2) | ((uint32_t)f2bf(v3)<<16);
          *(uint2*)&tile[(wid*16 + nn)*132 + m0 + q*4] = wv;
        }
      }
      __syncthreads();
      const int c = tid >> 1, half = tid & 1;
      float s = 0.f, q2 = 0.f, mx = -1e30f;
      #pragma unroll 4
      for (int it=0; it<32; it++){
        float f = bf2f(tile[(half*32 + it)*132 + c]);
        s += f; q2 = fmaf(f,f,q2); mx = fmaxf(mx, f);
      }
      rawmax[(size_t)(u*2 + half)*128 + c] = f2bf(mx);
      s  += __shfl_xor(s, 1, 64);
      q2 += __shfl_xor(q2, 1, 64);
      if (half==0){
        int rep = u & 7;
        atomicAdd(&st[512  + rep*128 + c], s);
        atomicAdd(&st[1536 + rep*128 + c], q2);
      }
    }
  }
  gridg.sync();

  // ---------------- phase 6: finalize ----------------
  {
    float (*tile)[65] = (float(*)[65])smraw;       // 16640 B
    float* aAl = (float*)(smraw + 16640);
    float* aBl = (float*)(smraw + 17152);
    if (tid < 128){
      float s=0.f, qv=0.f;
      #pragma unroll
      for (int r=0;r<8;r++){ s += st[512 + r*128 + tid]; qv += st[1536 + r*128 + tid]; }
      float mean = s * (1.f/PTOT);
      float var  = qv * (1.f/PTOT) - mean*mean;
      float a = g2v[tid] * rsqrtf(var + EPSV);
      aAl[tid] = a;
      aBl[tid] = fmaf(-mean, a, bt2[tid]);
    }
    float* outf = out + NB*3*NS;
    for (int u = blk; u < 256; u += G){
      __syncthreads();
      const int b  = u >> 4;
      const int ct = (u >> 3) & 1;
      const int stt = u & 7;
      const int c0 = ct*64, s0 = stt*64;
      #pragma unroll
      for (int r=0;r<16;r++){
        int sl = r*4 + wid;
        tile[sl][lane] = bf2f(rawmax[((size_t)(b*512 + s0 + sl))*128 + c0 + lane]);
      }
      __syncthreads();
      #pragma unroll
      for (int r=0;r<16;r++){
        int cl = r*4 + wid;
        float a = aAl[c0+cl], bb = aBl[c0+cl];
        outf[((size_t)(b*128 + c0 + cl))*512 + s0 + lane] = fmaxf(fmaf(tile[lane][cl], a, bb), 0.f);
      }
    }
  }
}

extern "C" void kernel_launch(void* const* d_in, const int* in_sizes, int n_in,
                              void* d_out, int out_size, void* d_ws, size_t ws_size,
                              hipStream_t stream) {
  const float* xyz = (const float*)d_in[0];
  const float* pts = (const float*)d_in[1];
  const float* w0  = (const float*)d_in[2];
  const float* b0  = (const float*)d_in[3];
  const float* g0  = (const float*)d_in[4];
  const float* bt0 = (const float*)d_in[5];
  const float* w1  = (const float*)d_in[6];
  const float* b1  = (const float*)d_in[7];
  const float* g1  = (const float*)d_in[8];
  const float* bt1 = (const float*)d_in[9];
  const float* w2  = (const float*)d_in[10];
  const float* b2  = (const float*)d_in[11];
  const float* g2  = (const float*)d_in[12];
  const float* bt2 = (const float*)d_in[13];
  float* out = (float*)d_out;
  float* ws  = (float*)d_ws;

  int nb = 0;
  if (hipOccupancyMaxActiveBlocksPerMultiprocessor(&nb, (const void*)mega_kernel, 256, 0) != hipSuccess || nb < 1)
    nb = 1;
  int grid = nb * 256;
  if (grid > 1024) grid = 1024;

  void* args[] = { (void*)&xyz, (void*)&pts,
                   (void*)&w0, (void*)&b0, (void*)&g0, (void*)&bt0,
                   (void*)&w1, (void*)&b1, (void*)&g1, (void*)&bt1,
                   (void*)&w2, (void*)&b2, (void*)&g2, (void*)&bt2,
                   (void*)&out, (void*)&ws };
  hipLaunchCooperativeKernel((void*)mega_kernel, dim3(grid), dim3(256), args, 0, stream);
}

// Round 12
// 447.648 us; speedup vs baseline: 1.5328x; 1.5328x over previous
//
#include <hip/hip_runtime.h>
#include <hip/hip_bf16.h>
#include <stdint.h>

#define NB 16
#define NPT 2048
#define NS 512
#define NK 32
#define PTOT (NB*NS*NK)   // 262144 positions
#define EPSV 1e-5f

typedef __attribute__((ext_vector_type(8))) short short8;
typedef __attribute__((ext_vector_type(4))) float floatx4;

// ws layout (float indices)
#define WS_NEWXYZ 0            // 24576
// ST: L1 sum 2x64@0 sq@128 | L2 sum 2x64@256 sq@384 | L3 sum 8x128@512 sq 8x128@1536 -> 2560
#define WS_ST     24576        // -> 27136
#define WS_W1BF   27136        // 4096 bf16 -> 29184
#define WS_W2BF   29184        // 8192 bf16 -> 33280
#define WS_W0R    33280        // 64x96 bf16 = 3072 fl -> 36352
#define WS_RAWMAX 36352        // 1048576 bf16 -> 560640
#define WS_PTS_TB 560640       // B*N*64 bf16 -> 1609216
#define WS_Y1     1609216      // 64*PTOT bf16 = 8388608 fl -> 9997824
#define WS_Y2     9997824      // -> 18386432  (~74MB)

__device__ __forceinline__ float bf2f(ushort u){ return __uint_as_float((uint32_t)u<<16); }
__device__ __forceinline__ ushort f2bf(float f){
  uint32_t u = __float_as_uint(f);
  return (ushort)((u + 0x7FFFu + ((u>>16)&1u)) >> 16);
}

template<int CTRL>
__device__ __forceinline__ double dppmax64f(double k){
  long long b = __double_as_longlong(k);
  int lo = (int)(uint32_t)b, hi = (int)(b>>32);
  int olo = __builtin_amdgcn_update_dpp(lo, lo, CTRL, 0xF, 0xF, false);
  int ohi = __builtin_amdgcn_update_dpp(hi, hi, CTRL, 0xF, 0xF, false);
  double o = __hiloint2double(ohi, olo);
  return fmax(o, k);
}

// ---------------- prep: fps (0-15) + transpose->bf16 (16-527) + wprep (528) ----------------
__global__ __launch_bounds__(256) void prep_kernel(const float* __restrict__ xyz,
    float* __restrict__ nxyz, float* __restrict__ out0,
    const float* __restrict__ pts, ushort* __restrict__ pts_tb,
    const float* __restrict__ w0, const float* __restrict__ w1, const float* __restrict__ w2,
    ushort* __restrict__ w0r, ushort* __restrict__ w1b, ushort* __restrict__ w2b,
    float* __restrict__ st)
{
  __shared__ union {
    struct { float4 lc[NPT]; double warrK[2][4]; float4 warrC[2][4]; float4 csel[NS]; } f;
    float tile[64][65];
  } sm;
  const int blk = blockIdx.x;
  const int tid = threadIdx.x;
  if (blk < 16){
    const int b = blk;
    const float* xb = xyz + (size_t)b*3*NPT;
    float px[8], py[8], pz[8], dist[8];
    uint32_t lo_[8];
    #pragma unroll
    for (int j=0;j<8;j++){
      int n = j*256 + tid;
      float x = xb[n], y = xb[NPT+n], z = xb[2*NPT+n];
      sm.f.lc[n] = make_float4(x,y,z,0.f);
      px[j]=x; py[j]=y; pz[j]=z; dist[j]=1e10f;
      lo_[j] = ~(uint32_t)n;
    }
    __syncthreads();
    float4 c0 = sm.f.lc[0];
    float cx = c0.x, cy = c0.y, cz = c0.z;
    if (tid==0) sm.f.csel[0] = make_float4(cx,cy,cz,0.f);
    const int lane = tid & 63, wid = tid >> 6;
    for (int t=1;t<NS;t++){
      double kk[8];
      #pragma unroll
      for (int j=0;j<8;j++){
        float dx = __fsub_rn(px[j], cx);
        float dy = __fsub_rn(py[j], cy);
        float dz = __fsub_rn(pz[j], cz);
        float d  = __fadd_rn(__fadd_rn(__fmul_rn(dx,dx),__fmul_rn(dy,dy)),__fmul_rn(dz,dz));
        float dd = fminf(dist[j], d);
        dist[j] = dd;
        kk[j] = __hiloint2double((int)__float_as_uint(dd), (int)lo_[j]);
      }
      double m0 = fmax(kk[0],kk[1]), m1 = fmax(kk[2],kk[3]);
      double m2 = fmax(kk[4],kk[5]), m3 = fmax(kk[6],kk[7]);
      double best = fmax(fmax(m0,m1), fmax(m2,m3));
      best = dppmax64f<0xB1>(best);    // quad xor1
      best = dppmax64f<0x4E>(best);    // quad xor2
      best = dppmax64f<0x124>(best);   // row_ror:4
      best = dppmax64f<0x128>(best);   // row_ror:8
      best = dppmax64f<0x142>(best);   // row_bcast15
      best = dppmax64f<0x143>(best);   // row_bcast31 -> lane63 = wave max
      long long bb = __double_as_longlong(best);
      int bl = (int)(uint32_t)bb, bh = (int)(bb>>32);
      uint32_t lo63 = (uint32_t)__builtin_amdgcn_readlane(bl, 63);
      uint32_t hi63 = (uint32_t)__builtin_amdgcn_readlane(bh, 63);
      int n_w = (int)(~lo63);                    // wave candidate index (uniform)
      float4 cw = sm.f.lc[n_w];                  // prefetch candidate coords (overlaps barrier)
      const int tb = t & 1;
      if (lane==0){
        sm.f.warrK[tb][wid] = __hiloint2double((int)hi63, (int)lo63);
        sm.f.warrC[tb][wid] = cw;
      }
      __syncthreads();
      double k0 = sm.f.warrK[tb][0], k1 = sm.f.warrK[tb][1];
      double k2 = sm.f.warrK[tb][2], k3 = sm.f.warrK[tb][3];
      float4 cc0 = sm.f.warrC[tb][0], cc1 = sm.f.warrC[tb][1];
      float4 cc2 = sm.f.warrC[tb][2], cc3 = sm.f.warrC[tb][3];
      if (k1 > k0){ k0 = k1; cc0 = cc1; }
      if (k3 > k2){ k2 = k3; cc2 = cc3; }
      if (k2 > k0){ k0 = k2; cc0 = cc2; }
      cx = cc0.x; cy = cc0.y; cz = cc0.z;
      if (tid==0) sm.f.csel[t] = make_float4(cx,cy,cz,0.f);
    }
    __syncthreads();
    for (int s = tid; s < NS; s += 256){
      float4 cc = sm.f.csel[s];
      float* np_ = nxyz + ((size_t)b*NS + s)*3;
      np_[0]=cc.x; np_[1]=cc.y; np_[2]=cc.z;
      float* ob = out0 + (size_t)b*3*NS + s;
      ob[0]=cc.x; ob[NS]=cc.y; ob[2*NS]=cc.z;
    }
  } else if (blk < 528){
    const int t2 = blk - 16;
    const int b = t2 >> 5;
    const int n0 = (t2 & 31) * 64;
    const int lane = tid & 63;
    const int row4 = tid >> 6;
    const float* src = pts + (size_t)b*64*NPT;
    #pragma unroll
    for (int r=0; r<16; r++){
      int cc = r*4 + row4;
      sm.tile[cc][lane] = src[(size_t)cc*NPT + n0 + lane];
    }
    __syncthreads();
    ushort* dst = pts_tb + ((size_t)b*NPT + n0)*64;
    #pragma unroll
    for (int r=0; r<16; r++){
      int nn = r*4 + row4;
      dst[(size_t)nn*64 + lane] = f2bf(sm.tile[lane][nn]);
    }
  } else {
    for (int i = tid; i < 4096; i += 256) w1b[i] = f2bf(w1[i]);
    for (int i = tid; i < 8192; i += 256) w2b[i] = f2bf(w2[i]);
    for (int i = tid; i < 2560; i += 256) st[i] = 0.f;
    // w0 reorder: col 0-63 = pts weights (w0 col 3..66), 64-66 = xyz weights, 67-95 = 0
    for (int i = tid; i < 6144; i += 256){
      int o = i / 96, k = i - o*96;
      float v = (k < 64) ? w0[o*67 + 3 + k] : ((k < 67) ? w0[o*67 + (k-64)] : 0.f);
      w0r[i] = f2bf(v);
    }
  }
}

// ---------------- conv1 MFMA: ballq (per-wave) + 96->64, pm-bf16 out ----------------
__global__ __launch_bounds__(256) void conv1_mfma(const float* __restrict__ xyz,
    const ushort* __restrict__ pts_tb, const float* __restrict__ nxyz,
    const ushort* __restrict__ w0r, const float* __restrict__ b0,
    ushort* __restrict__ y1)
{
  __shared__ int gq[4][NK];
  const int tid = threadIdx.x;
  const int wid = tid>>6, lane = tid&63;
  const int q = lane>>4, nn = lane&15;
  const int g = blockIdx.x*4 + wid;          // group 0..8191
  const int b = g >> 9;
  const float* xb = xyz + (size_t)b*3*NPT;
  const float* cgp = nxyz + (size_t)g*3;
  const float cx = cgp[0], cy = cgp[1], cz = cgp[2];
  {
    const float r2 = 0.2f*0.2f;
    int cnt = 0, first = 0;
    for (int ch=0; ch<NPT/64 && cnt<NK; ch++){
      int n = ch*64 + lane;
      float dx = __fsub_rn(cx, xb[n]);
      float dy = __fsub_rn(cy, xb[NPT+n]);
      float dz = __fsub_rn(cz, xb[2*NPT+n]);
      float d  = __fadd_rn(__fadd_rn(__fmul_rn(dx,dx),__fmul_rn(dy,dy)),__fmul_rn(dz,dz));
      bool in = (d <= r2);
      unsigned long long mask = __ballot(in);
      if (mask){
        if (cnt==0) first = ch*64 + (__ffsll((unsigned long long)mask)-1);
        if (in){
          int pos = cnt + __popcll(mask & ((1ull<<lane)-1ull));
          if (pos < NK) gq[wid][pos] = n;
        }
        cnt += __popcll(mask);
      }
    }
    if (cnt < NK && lane >= cnt && lane < NK) gq[wid][lane] = first;
  }
  int n0 = gq[wid][nn], n1 = gq[wid][16+nn];
  float dx0 = xb[n0]-cx, dy0 = xb[NPT+n0]-cy, dz0 = xb[2*NPT+n0]-cz;
  float dx1 = xb[n1]-cx, dy1 = xb[NPT+n1]-cy, dz1 = xb[2*NPT+n1]-cz;
  floatx4 z4 = {0.f,0.f,0.f,0.f};
  floatx4 acc[4][2];
  #pragma unroll
  for (int mt=0;mt<4;mt++){ acc[mt][0]=z4; acc[mt][1]=z4; }
  const ushort* pr0 = pts_tb + ((size_t)b*NPT + n0)*64;
  const ushort* pr1 = pts_tb + ((size_t)b*NPT + n1)*64;
  #pragma unroll
  for (int kh=0; kh<2; kh++){
    short8 B0 = *(const short8*)(pr0 + kh*32 + q*8);
    short8 B1 = *(const short8*)(pr1 + kh*32 + q*8);
    #pragma unroll
    for (int mt=0; mt<4; mt++){
      short8 A = *(const short8*)(w0r + (mt*16+nn)*96 + kh*32 + q*8);
      acc[mt][0] = __builtin_amdgcn_mfma_f32_16x16x32_bf16(A, B0, acc[mt][0], 0,0,0);
      acc[mt][1] = __builtin_amdgcn_mfma_f32_16x16x32_bf16(A, B1, acc[mt][1], 0,0,0);
    }
  }
  {
    short8 B0 = {0,0,0,0,0,0,0,0}, B1 = {0,0,0,0,0,0,0,0};
    if (q==0){
      B0[0]=(short)f2bf(dx0); B0[1]=(short)f2bf(dy0); B0[2]=(short)f2bf(dz0);
      B1[0]=(short)f2bf(dx1); B1[1]=(short)f2bf(dy1); B1[2]=(short)f2bf(dz1);
    }
    #pragma unroll
    for (int mt=0; mt<4; mt++){
      short8 A = *(const short8*)(w0r + (mt*16+nn)*96 + 64 + q*8);
      acc[mt][0] = __builtin_amdgcn_mfma_f32_16x16x32_bf16(A, B0, acc[mt][0], 0,0,0);
      acc[mt][1] = __builtin_amdgcn_mfma_f32_16x16x32_bf16(A, B1, acc[mt][1], 0,0,0);
    }
  }
  float bias_[4][4];
  #pragma unroll
  for (int mt=0;mt<4;mt++)
    #pragma unroll
    for (int r=0;r<4;r++) bias_[mt][r] = b0[mt*16 + q*4 + r];
  #pragma unroll
  for (int nt=0; nt<2; nt++){
    int p = g*32 + nt*16 + nn;
    #pragma unroll
    for (int mt=0; mt<4; mt++){
      float v0 = acc[mt][nt][0] + bias_[mt][0];
      float v1 = acc[mt][nt][1] + bias_[mt][1];
      float v2 = acc[mt][nt][2] + bias_[mt][2];
      float v3 = acc[mt][nt][3] + bias_[mt][3];
      uint2 wv;
      wv.x = (uint32_t)f2bf(v0) | ((uint32_t)f2bf(v1)<<16);
      wv.y = (uint32_t)f2bf(v2) | ((uint32_t)f2bf(v3)<<16);
      *(uint2*)(y1 + (size_t)p*64 + mt*16 + q*4) = wv;
    }
  }
}

// ---------------- stats over 64-ch pm-bf16: 256 blocks, replicated atomic sums ----------------
__global__ __launch_bounds__(256) void stats64_kernel(const ushort* __restrict__ y,
                                                      float* __restrict__ stbase)
{
  const int wid = threadIdx.x>>6, lane = threadIdx.x&63;
  const int oct = lane & 7, pr = lane >> 3;
  const int p0 = blockIdx.x*1024 + wid*256;
  float s[8], s2[8];
  #pragma unroll
  for (int j=0;j<8;j++){ s[j]=0.f; s2[j]=0.f; }
  for (int it=0; it<32; it++){
    int p = p0 + it*8 + pr;
    short8 v = *(const short8*)(y + (size_t)p*64 + oct*8);
    #pragma unroll
    for (int j=0;j<8;j++){
      float f = bf2f((ushort)v[j]);
      s[j] += f; s2[j] = fmaf(f,f,s2[j]);
    }
  }
  #pragma unroll
  for (int off=8; off<64; off<<=1){
    #pragma unroll
    for (int j=0;j<8;j++){ s[j] += __shfl_xor(s[j],off,64); s2[j] += __shfl_xor(s2[j],off,64); }
  }
  __shared__ float sd[4][128];
  if (pr==0){
    #pragma unroll
    for (int j=0;j<8;j++){ sd[wid][oct*8+j] = s[j]; sd[wid][64+oct*8+j] = s2[j]; }
  }
  __syncthreads();
  int t = threadIdx.x;
  if (t < 128){
    float v = sd[0][t]+sd[1][t]+sd[2][t]+sd[3][t];
    int rep = blockIdx.x & 1;
    float* dst = (t<64) ? (stbase + rep*64 + t) : (stbase + 128 + rep*64 + (t-64));
    atomicAdd(dst, v);
  }
}

// ---------------- conv2 MFMA: 64->64, affine prologue ----------------
__global__ __launch_bounds__(256) void conv2_mfma(const ushort* __restrict__ yin,
    const float* __restrict__ st, const float* __restrict__ g0, const float* __restrict__ bt0,
    const ushort* __restrict__ Wb, const float* __restrict__ bias,
    ushort* __restrict__ yout)
{
  __shared__ float aAl[64], aBl[64];
  const int tid = threadIdx.x;
  if (tid < 64){
    float s = st[tid] + st[64+tid];
    float qv = st[128+tid] + st[192+tid];
    float mean = s * (1.f/PTOT);
    float var  = qv * (1.f/PTOT) - mean*mean;
    float a = g0[tid] * rsqrtf(var + EPSV);
    aAl[tid] = a;
    aBl[tid] = fmaf(-mean, a, bt0[tid]);
  }
  __syncthreads();
  const int wid = tid>>6, lane = tid&63;
  const int q = lane>>4, nn = lane&15;
  const int p0 = (blockIdx.x*4 + wid) * 32;
  float a_[2][8], b_[2][8];
  #pragma unroll
  for (int kh=0;kh<2;kh++)
    #pragma unroll
    for (int j=0;j<8;j++){
      a_[kh][j] = aAl[kh*32 + q*8 + j];
      b_[kh][j] = aBl[kh*32 + q*8 + j];
    }
  short8 Af[4][2];
  #pragma unroll
  for (int mt=0;mt<4;mt++)
    #pragma unroll
    for (int kh=0;kh<2;kh++)
      Af[mt][kh] = *(const short8*)(Wb + (mt*16 + nn)*64 + kh*32 + q*8);
  float bias_[4][4];
  #pragma unroll
  for (int mt=0;mt<4;mt++)
    #pragma unroll
    for (int r=0;r<4;r++) bias_[mt][r] = bias[mt*16 + q*4 + r];
  floatx4 z = {0.f,0.f,0.f,0.f};
  floatx4 acc[4][2];
  #pragma unroll
  for (int mt=0;mt<4;mt++){ acc[mt][0]=z; acc[mt][1]=z; }
  #pragma unroll
  for (int nt=0;nt<2;nt++){
    #pragma unroll
    for (int kh=0;kh<2;kh++){
      short8 raw = *(const short8*)(yin + (size_t)(p0 + nt*16 + nn)*64 + kh*32 + q*8);
      short8 bf;
      #pragma unroll
      for (int j=0;j<8;j++){
        float f = bf2f((ushort)raw[j]);
        f = fmaxf(fmaf(f, a_[kh][j], b_[kh][j]), 0.f);
        bf[j] = (short)f2bf(f);
      }
      #pragma unroll
      for (int mt=0;mt<4;mt++)
        acc[mt][nt] = __builtin_amdgcn_mfma_f32_16x16x32_bf16(Af[mt][kh], bf, acc[mt][nt], 0,0,0);
    }
  }
  #pragma unroll
  for (int nt=0;nt<2;nt++){
    int p = p0 + nt*16 + nn;
    #pragma unroll
    for (int mt=0;mt<4;mt++){
      float v0 = acc[mt][nt][0] + bias_[mt][0];
      float v1 = acc[mt][nt][1] + bias_[mt][1];
      float v2 = acc[mt][nt][2] + bias_[mt][2];
      float v3 = acc[mt][nt][3] + bias_[mt][3];
      uint2 w;
      w.x = (uint32_t)f2bf(v0) | ((uint32_t)f2bf(v1)<<16);
      w.y = (uint32_t)f2bf(v2) | ((uint32_t)f2bf(v3)<<16);
      *(uint2*)(yout + (size_t)p*64 + mt*16 + q*4) = w;
    }
  }
}

// ---------------- conv3 MFMA: 64->128, tile in LDS, fused group-max + L3 stats ----------------
__global__ __launch_bounds__(256) void conv3_mfma(const ushort* __restrict__ yin,
    float* __restrict__ st, const float* __restrict__ g1, const float* __restrict__ bt1,
    const ushort* __restrict__ Wb, const float* __restrict__ bias,
    ushort* __restrict__ rawmax)
{
  __shared__ ushort tile[64*132];   // 64 pos x 128 ch, pitch 132
  __shared__ float aAl[64], aBl[64];
  const int tid = threadIdx.x;
  if (tid < 64){
    float s = st[256+tid] + st[320+tid];
    float qv = st[384+tid] + st[448+tid];
    float mean = s * (1.f/PTOT);
    float var  = qv * (1.f/PTOT) - mean*mean;
    float a = g1[tid] * rsqrtf(var + EPSV);
    aAl[tid] = a;
    aBl[tid] = fmaf(-mean, a, bt1[tid]);
  }
  __syncthreads();
  const int wid = tid>>6, lane = tid&63;
  const int q = lane>>4, nn = lane&15;
  const int p0 = (blockIdx.x*4 + wid) * 16;
  float a_[2][8], b_[2][8];
  #pragma unroll
  for (int kh=0;kh<2;kh++)
    #pragma unroll
    for (int j=0;j<8;j++){
      a_[kh][j] = aAl[kh*32 + q*8 + j];
      b_[kh][j] = aBl[kh*32 + q*8 + j];
    }
  short8 bfr[2];
  #pragma unroll
  for (int kh=0;kh<2;kh++){
    short8 raw = *(const short8*)(yin + (size_t)(p0 + nn)*64 + kh*32 + q*8);
    short8 bf;
    #pragma unroll
    for (int j=0;j<8;j++){
      float f = bf2f((ushort)raw[j]);
      f = fmaxf(fmaf(f, a_[kh][j], b_[kh][j]), 0.f);
      bf[j] = (short)f2bf(f);
    }
    bfr[kh] = bf;
  }
  #pragma unroll 1
  for (int mh=0;mh<2;mh++){
    floatx4 z = {0.f,0.f,0.f,0.f};
    floatx4 acc[4];
    short8 Af[4][2];
    #pragma unroll
    for (int mt=0;mt<4;mt++){
      acc[mt]=z;
      #pragma unroll
      for (int kh=0;kh<2;kh++)
        Af[mt][kh] = *(const short8*)(Wb + ((mh*4+mt)*16 + nn)*64 + kh*32 + q*8);
    }
    #pragma unroll
    for (int kh=0;kh<2;kh++)
      #pragma unroll
      for (int mt=0;mt<4;mt++)
        acc[mt] = __builtin_amdgcn_mfma_f32_16x16x32_bf16(Af[mt][kh], bfr[kh], acc[mt], 0,0,0);
    #pragma unroll
    for (int mt=0;mt<4;mt++){
      int m0 = (mh*4+mt)*16;
      float v0 = acc[mt][0] + bias[m0 + q*4 + 0];
      float v1 = acc[mt][1] + bias[m0 + q*4 + 1];
      float v2 = acc[mt][2] + bias[m0 + q*4 + 2];
      float v3 = acc[mt][3] + bias[m0 + q*4 + 3];
      uint2 w;
      w.x = (uint32_t)f2bf(v0) | ((uint32_t)f2bf(v1)<<16);
      w.y = (uint32_t)f2bf(v2) | ((uint32_t)f2bf(v3)<<16);
      *(uint2*)&tile[(wid*16 + nn)*132 + m0 + q*4] = w;
    }
  }
  __syncthreads();
  const int c = tid >> 1, half = tid & 1;
  float s = 0.f, q2 = 0.f, mx = -1e30f;
  #pragma unroll 4
  for (int it=0; it<32; it++){
    float f = bf2f(tile[(half*32 + it)*132 + c]);
    s += f; q2 = fmaf(f,f,q2); mx = fmaxf(mx, f);
  }
  rawmax[(size_t)(blockIdx.x*2 + half)*128 + c] = f2bf(mx);
  s  += __shfl_xor(s, 1, 64);
  q2 += __shfl_xor(q2, 1, 64);
  if (half==0){
    int rep = blockIdx.x & 7;
    atomicAdd(&st[512  + rep*128 + c], s);
    atomicAdd(&st[1536 + rep*128 + c], q2);
  }
}

// ---------------- finalize: tiled transpose + affine+relu ----------------
__global__ __launch_bounds__(256) void finalize_kernel(const ushort* __restrict__ rawmax,
    const float* __restrict__ st, const float* __restrict__ g2, const float* __restrict__ bt2,
    float* __restrict__ out)
{
  __shared__ float tile[64][65];
  __shared__ float aAl[128], aBl[128];
  const int tid = threadIdx.x;
  if (tid < 128){
    float s=0.f, qv=0.f;
    #pragma unroll
    for (int r=0;r<8;r++){ s += st[512 + r*128 + tid]; qv += st[1536 + r*128 + tid]; }
    float mean = s * (1.f/PTOT);
    float var  = qv * (1.f/PTOT) - mean*mean;
    float a = g2[tid] * rsqrtf(var + EPSV);
    aAl[tid] = a;
    aBl[tid] = fmaf(-mean, a, bt2[tid]);
  }
  __syncthreads();
  const int b  = blockIdx.x >> 4;
  const int ct = (blockIdx.x >> 3) & 1;
  const int stt = blockIdx.x & 7;
  const int c0 = ct*64, s0 = stt*64;
  const int lane = tid & 63, wid = tid >> 6;
  #pragma unroll
  for (int r=0;r<16;r++){
    int sl = r*4 + wid;
    tile[sl][lane] = bf2f(rawmax[((size_t)(b*512 + s0 + sl))*128 + c0 + lane]);
  }
  __syncthreads();
  #pragma unroll
  for (int r=0;r<16;r++){
    int cl = r*4 + wid;
    float a = aAl[c0+cl], bb = aBl[c0+cl];
    out[((size_t)(b*128 + c0 + cl))*512 + s0 + lane] = fmaxf(fmaf(tile[lane][cl], a, bb), 0.f);
  }
}

extern "C" void kernel_launch(void* const* d_in, const int* in_sizes, int n_in,
                              void* d_out, int out_size, void* d_ws, size_t ws_size,
                              hipStream_t stream) {
  const float* xyz = (const float*)d_in[0];
  const float* pts = (const float*)d_in[1];
  const float* w0  = (const float*)d_in[2];
  const float* b0  = (const float*)d_in[3];
  const float* g0  = (const float*)d_in[4];
  const float* bt0 = (const float*)d_in[5];
  const float* w1  = (const float*)d_in[6];
  const float* b1  = (const float*)d_in[7];
  const float* g1  = (const float*)d_in[8];
  const float* bt1 = (const float*)d_in[9];
  const float* w2  = (const float*)d_in[10];
  const float* b2  = (const float*)d_in[11];
  const float* g2  = (const float*)d_in[12];
  const float* bt2 = (const float*)d_in[13];
  float* out = (float*)d_out;
  float* ws  = (float*)d_ws;

  float* nxyz = ws + WS_NEWXYZ;
  float* st   = ws + WS_ST;
  ushort* w0r = (ushort*)(ws + WS_W0R);
  ushort* w1b = (ushort*)(ws + WS_W1BF);
  ushort* w2b = (ushort*)(ws + WS_W2BF);
  ushort* rawmax = (ushort*)(ws + WS_RAWMAX);
  ushort* pts_tb = (ushort*)(ws + WS_PTS_TB);
  ushort* y1 = (ushort*)(ws + WS_Y1);
  ushort* y2 = (ushort*)(ws + WS_Y2);

  prep_kernel<<<529,256,0,stream>>>(xyz, nxyz, out, pts, pts_tb, w0, w1, w2, w0r, w1b, w2b, st);
  conv1_mfma<<<2048,256,0,stream>>>(xyz, pts_tb, nxyz, w0r, b0, y1);
  stats64_kernel<<<256,256,0,stream>>>(y1, st);
  conv2_mfma<<<2048,256,0,stream>>>(y1, st, g0, bt0, w1b, b1, y2);
  stats64_kernel<<<256,256,0,stream>>>(y2, st + 256);
  conv3_mfma<<<4096,256,0,stream>>>(y2, st, g1, bt1, w2b, b2, rawmax);
  finalize_kernel<<<256,256,0,stream>>>(rawmax, st, g2, bt2, out + NB*3*NS);
}

// Round 13
// 430.213 us; speedup vs baseline: 1.5949x; 1.0405x over previous
//
#include <hip/hip_runtime.h>
#include <hip/hip_bf16.h>
#include <stdint.h>

#define NB 16
#define NPT 2048
#define NS 512
#define NK 32
#define PTOT (NB*NS*NK)   // 262144 positions
#define EPSV 1e-5f

typedef __attribute__((ext_vector_type(8))) short short8;
typedef __attribute__((ext_vector_type(4))) float floatx4;

// ws layout (float indices)
#define WS_NEWXYZ 0            // 24576
// ST: L1 sum 2x64@0 sq@128 | L2 sum 2x64@256 sq@384 | L3 sum 8x128@512 sq 8x128@1536 -> 2560
#define WS_ST     24576        // -> 27136
#define WS_W1BF   27136        // 4096 bf16 -> 29184
#define WS_W2BF   29184        // 8192 bf16 -> 33280
#define WS_W0R    33280        // 64x96 bf16 = 3072 fl -> 36352
#define WS_RAWMAX 36352        // 1048576 bf16 -> 560640
#define WS_PTS_TB 560640       // B*N*64 bf16 -> 1609216
#define WS_Y1     1609216      // 64*PTOT bf16 = 8388608 fl -> 9997824
#define WS_Y2     9997824      // -> 18386432  (~74MB)

__device__ __forceinline__ float bf2f(ushort u){ return __uint_as_float((uint32_t)u<<16); }
__device__ __forceinline__ ushort f2bf(float f){
  uint32_t u = __float_as_uint(f);
  return (ushort)((u + 0x7FFFu + ((u>>16)&1u)) >> 16);
}

template<int CTRL>
__device__ __forceinline__ double dppmax64f(double k){
  long long b = __double_as_longlong(k);
  int lo = (int)(uint32_t)b, hi = (int)(b>>32);
  int olo = __builtin_amdgcn_update_dpp(lo, lo, CTRL, 0xF, 0xF, false);
  int ohi = __builtin_amdgcn_update_dpp(hi, hi, CTRL, 0xF, 0xF, false);
  double o = __hiloint2double(ohi, olo);
  return fmax(o, k);
}
__device__ __forceinline__ unsigned long long u64max(unsigned long long a, unsigned long long b){ return a>b?a:b; }

// ---------------- prep: fps (0-15, r3 body) + transpose->bf16 (16-527) + wprep (528) ----------------
__global__ __launch_bounds__(256) void prep_kernel(const float* __restrict__ xyz,
    float* __restrict__ nxyz, float* __restrict__ out0,
    const float* __restrict__ pts, ushort* __restrict__ pts_tb,
    const float* __restrict__ w0, const float* __restrict__ w1, const float* __restrict__ w2,
    ushort* __restrict__ w0r, ushort* __restrict__ w1b, ushort* __restrict__ w2b,
    float* __restrict__ st)
{
  __shared__ union {
    struct { float4 lc[NPT]; double warr[2][4]; int sel[NS]; } f;
    float tile[64][65];
  } sm;
  const int blk = blockIdx.x;
  const int tid = threadIdx.x;
  if (blk < 16){
    // ---- FPS: exact r3 body (measured 223us in r8/r10) ----
    const int b = blk;
    const float* xb = xyz + (size_t)b*3*NPT;
    float px[8], py[8], pz[8], dist[8];
    uint32_t lo_[8];
    #pragma unroll
    for (int j=0;j<8;j++){
      int n = j*256 + tid;
      float x = xb[n], y = xb[NPT+n], z = xb[2*NPT+n];
      sm.f.lc[n] = make_float4(x,y,z,0.f);
      px[j]=x; py[j]=y; pz[j]=z; dist[j]=1e10f;
      lo_[j] = ~(uint32_t)n;
    }
    if (tid==0) sm.f.sel[0]=0;
    __syncthreads();
    float4 c0 = sm.f.lc[0];
    float cx = c0.x, cy = c0.y, cz = c0.z;
    const int lane = tid & 63, wid = tid >> 6;
    for (int t=1;t<NS;t++){
      double kk[8];
      #pragma unroll
      for (int j=0;j<8;j++){
        float dx = __fsub_rn(px[j], cx);
        float dy = __fsub_rn(py[j], cy);
        float dz = __fsub_rn(pz[j], cz);
        float d  = __fadd_rn(__fadd_rn(__fmul_rn(dx,dx),__fmul_rn(dy,dy)),__fmul_rn(dz,dz));
        float dd = fminf(dist[j], d);
        dist[j] = dd;
        kk[j] = __hiloint2double((int)__float_as_uint(dd), (int)lo_[j]);
      }
      double m0 = fmax(kk[0],kk[1]), m1 = fmax(kk[2],kk[3]);
      double m2 = fmax(kk[4],kk[5]), m3 = fmax(kk[6],kk[7]);
      double best = fmax(fmax(m0,m1), fmax(m2,m3));
      best = dppmax64f<0xB1>(best);    // quad xor1
      best = dppmax64f<0x4E>(best);    // quad xor2
      best = dppmax64f<0x124>(best);   // row_ror:4
      best = dppmax64f<0x128>(best);   // row_ror:8  -> each row16 has its max
      long long bb = __double_as_longlong(best);
      int bl = (int)(uint32_t)bb, bh = (int)(bb>>32);
      unsigned long long k0 = (((unsigned long long)(uint32_t)__builtin_amdgcn_readlane(bh, 0))<<32)  | (uint32_t)__builtin_amdgcn_readlane(bl, 0);
      unsigned long long k1 = (((unsigned long long)(uint32_t)__builtin_amdgcn_readlane(bh, 16))<<32) | (uint32_t)__builtin_amdgcn_readlane(bl, 16);
      unsigned long long k2 = (((unsigned long long)(uint32_t)__builtin_amdgcn_readlane(bh, 32))<<32) | (uint32_t)__builtin_amdgcn_readlane(bl, 32);
      unsigned long long k3 = (((unsigned long long)(uint32_t)__builtin_amdgcn_readlane(bh, 48))<<32) | (uint32_t)__builtin_amdgcn_readlane(bl, 48);
      unsigned long long kw = u64max(u64max(k0,k1), u64max(k2,k3));
      if (lane==0) sm.f.warr[t&1][wid] = __longlong_as_double((long long)kw);
      __syncthreads();
      double w0_ = sm.f.warr[t&1][0], w1_ = sm.f.warr[t&1][1], w2_ = sm.f.warr[t&1][2], w3_ = sm.f.warr[t&1][3];
      double f = fmax(fmax(w0_,w1_), fmax(w2_,w3_));
      int n = (int)(~(uint32_t)__double_as_longlong(f));
      float4 cc = sm.f.lc[n];
      cx = cc.x; cy = cc.y; cz = cc.z;
      if (tid==0) sm.f.sel[t]=n;
    }
    __syncthreads();
    for (int s = tid; s < NS; s += 256){
      int n = sm.f.sel[s];
      float4 cc = sm.f.lc[n];
      float* np_ = nxyz + ((size_t)b*NS + s)*3;
      np_[0]=cc.x; np_[1]=cc.y; np_[2]=cc.z;
      float* ob = out0 + (size_t)b*3*NS + s;
      ob[0]=cc.x; ob[NS]=cc.y; ob[2*NS]=cc.z;
    }
  } else if (blk < 528){
    const int t2 = blk - 16;
    const int b = t2 >> 5;
    const int n0 = (t2 & 31) * 64;
    const int lane = tid & 63;
    const int row4 = tid >> 6;
    const float* src = pts + (size_t)b*64*NPT;
    #pragma unroll
    for (int r=0; r<16; r++){
      int cc = r*4 + row4;
      sm.tile[cc][lane] = src[(size_t)cc*NPT + n0 + lane];
    }
    __syncthreads();
    ushort* dst = pts_tb + ((size_t)b*NPT + n0)*64;
    #pragma unroll
    for (int r=0; r<16; r++){
      int nn = r*4 + row4;
      dst[(size_t)nn*64 + lane] = f2bf(sm.tile[lane][nn]);
    }
  } else {
    for (int i = tid; i < 4096; i += 256) w1b[i] = f2bf(w1[i]);
    for (int i = tid; i < 8192; i += 256) w2b[i] = f2bf(w2[i]);
    for (int i = tid; i < 2560; i += 256) st[i] = 0.f;
    // w0 reorder: col 0-63 = pts weights (w0 col 3..66), 64-66 = xyz weights, 67-95 = 0
    for (int i = tid; i < 6144; i += 256){
      int o = i / 96, k = i - o*96;
      float v = (k < 64) ? w0[o*67 + 3 + k] : ((k < 67) ? w0[o*67 + (k-64)] : 0.f);
      w0r[i] = f2bf(v);
    }
  }
}

// ---------------- conv1 MFMA: ballq (per-wave) + 96->64, pm-bf16 out ----------------
__global__ __launch_bounds__(256) void conv1_mfma(const float* __restrict__ xyz,
    const ushort* __restrict__ pts_tb, const float* __restrict__ nxyz,
    const ushort* __restrict__ w0r, const float* __restrict__ b0,
    ushort* __restrict__ y1)
{
  __shared__ int gq[4][NK];
  const int tid = threadIdx.x;
  const int wid = tid>>6, lane = tid&63;
  const int q = lane>>4, nn = lane&15;
  const int g = blockIdx.x*4 + wid;          // group 0..8191
  const int b = g >> 9;
  const float* xb = xyz + (size_t)b*3*NPT;
  const float* cgp = nxyz + (size_t)g*3;
  const float cx = cgp[0], cy = cgp[1], cz = cgp[2];
  {
    const float r2 = 0.2f*0.2f;
    int cnt = 0, first = 0;
    for (int ch=0; ch<NPT/64 && cnt<NK; ch++){
      int n = ch*64 + lane;
      float dx = __fsub_rn(cx, xb[n]);
      float dy = __fsub_rn(cy, xb[NPT+n]);
      float dz = __fsub_rn(cz, xb[2*NPT+n]);
      float d  = __fadd_rn(__fadd_rn(__fmul_rn(dx,dx),__fmul_rn(dy,dy)),__fmul_rn(dz,dz));
      bool in = (d <= r2);
      unsigned long long mask = __ballot(in);
      if (mask){
        if (cnt==0) first = ch*64 + (__ffsll((unsigned long long)mask)-1);
        if (in){
          int pos = cnt + __popcll(mask & ((1ull<<lane)-1ull));
          if (pos < NK) gq[wid][pos] = n;
        }
        cnt += __popcll(mask);
      }
    }
    if (cnt < NK && lane >= cnt && lane < NK) gq[wid][lane] = first;
  }
  int n0 = gq[wid][nn], n1 = gq[wid][16+nn];
  float dx0 = xb[n0]-cx, dy0 = xb[NPT+n0]-cy, dz0 = xb[2*NPT+n0]-cz;
  float dx1 = xb[n1]-cx, dy1 = xb[NPT+n1]-cy, dz1 = xb[2*NPT+n1]-cz;
  floatx4 z4 = {0.f,0.f,0.f,0.f};
  floatx4 acc[4][2];
  #pragma unroll
  for (int mt=0;mt<4;mt++){ acc[mt][0]=z4; acc[mt][1]=z4; }
  const ushort* pr0 = pts_tb + ((size_t)b*NPT + n0)*64;
  const ushort* pr1 = pts_tb + ((size_t)b*NPT + n1)*64;
  #pragma unroll
  for (int kh=0; kh<2; kh++){
    short8 B0 = *(const short8*)(pr0 + kh*32 + q*8);
    short8 B1 = *(const short8*)(pr1 + kh*32 + q*8);
    #pragma unroll
    for (int mt=0; mt<4; mt++){
      short8 A = *(const short8*)(w0r + (mt*16+nn)*96 + kh*32 + q*8);
      acc[mt][0] = __builtin_amdgcn_mfma_f32_16x16x32_bf16(A, B0, acc[mt][0], 0,0,0);
      acc[mt][1] = __builtin_amdgcn_mfma_f32_16x16x32_bf16(A, B1, acc[mt][1], 0,0,0);
    }
  }
  {
    short8 B0 = {0,0,0,0,0,0,0,0}, B1 = {0,0,0,0,0,0,0,0};
    if (q==0){
      B0[0]=(short)f2bf(dx0); B0[1]=(short)f2bf(dy0); B0[2]=(short)f2bf(dz0);
      B1[0]=(short)f2bf(dx1); B1[1]=(short)f2bf(dy1); B1[2]=(short)f2bf(dz1);
    }
    #pragma unroll
    for (int mt=0; mt<4; mt++){
      short8 A = *(const short8*)(w0r + (mt*16+nn)*96 + 64 + q*8);
      acc[mt][0] = __builtin_amdgcn_mfma_f32_16x16x32_bf16(A, B0, acc[mt][0], 0,0,0);
      acc[mt][1] = __builtin_amdgcn_mfma_f32_16x16x32_bf16(A, B1, acc[mt][1], 0,0,0);
    }
  }
  float bias_[4][4];
  #pragma unroll
  for (int mt=0;mt<4;mt++)
    #pragma unroll
    for (int r=0;r<4;r++) bias_[mt][r] = b0[mt*16 + q*4 + r];
  #pragma unroll
  for (int nt=0; nt<2; nt++){
    int p = g*32 + nt*16 + nn;
    #pragma unroll
    for (int mt=0; mt<4; mt++){
      float v0 = acc[mt][nt][0] + bias_[mt][0];
      float v1 = acc[mt][nt][1] + bias_[mt][1];
      float v2 = acc[mt][nt][2] + bias_[mt][2];
      float v3 = acc[mt][nt][3] + bias_[mt][3];
      uint2 wv;
      wv.x = (uint32_t)f2bf(v0) | ((uint32_t)f2bf(v1)<<16);
      wv.y = (uint32_t)f2bf(v2) | ((uint32_t)f2bf(v3)<<16);
      *(uint2*)(y1 + (size_t)p*64 + mt*16 + q*4) = wv;
    }
  }
}

// ---------------- stats over 64-ch pm-bf16: 256 blocks, replicated atomic sums ----------------
__global__ __launch_bounds__(256) void stats64_kernel(const ushort* __restrict__ y,
                                                      float* __restrict__ stbase)
{
  const int wid = threadIdx.x>>6, lane = threadIdx.x&63;
  const int oct = lane & 7, pr = lane >> 3;
  const int p0 = blockIdx.x*1024 + wid*256;
  float s[8], s2[8];
  #pragma unroll
  for (int j=0;j<8;j++){ s[j]=0.f; s2[j]=0.f; }
  for (int it=0; it<32; it++){
    int p = p0 + it*8 + pr;
    short8 v = *(const short8*)(y + (size_t)p*64 + oct*8);
    #pragma unroll
    for (int j=0;j<8;j++){
      float f = bf2f((ushort)v[j]);
      s[j] += f; s2[j] = fmaf(f,f,s2[j]);
    }
  }
  #pragma unroll
  for (int off=8; off<64; off<<=1){
    #pragma unroll
    for (int j=0;j<8;j++){ s[j] += __shfl_xor(s[j],off,64); s2[j] += __shfl_xor(s2[j],off,64); }
  }
  __shared__ float sd[4][128];
  if (pr==0){
    #pragma unroll
    for (int j=0;j<8;j++){ sd[wid][oct*8+j] = s[j]; sd[wid][64+oct*8+j] = s2[j]; }
  }
  __syncthreads();
  int t = threadIdx.x;
  if (t < 128){
    float v = sd[0][t]+sd[1][t]+sd[2][t]+sd[3][t];
    int rep = blockIdx.x & 1;
    float* dst = (t<64) ? (stbase + rep*64 + t) : (stbase + 128 + rep*64 + (t-64));
    atomicAdd(dst, v);
  }
}

// ---------------- conv2 MFMA: 64->64, affine prologue ----------------
__global__ __launch_bounds__(256) void conv2_mfma(const ushort* __restrict__ yin,
    const float* __restrict__ st, const float* __restrict__ g0, const float* __restrict__ bt0,
    const ushort* __restrict__ Wb, const float* __restrict__ bias,
    ushort* __restrict__ yout)
{
  __shared__ float aAl[64], aBl[64];
  const int tid = threadIdx.x;
  if (tid < 64){
    float s = st[tid] + st[64+tid];
    float qv = st[128+tid] + st[192+tid];
    float mean = s * (1.f/PTOT);
    float var  = qv * (1.f/PTOT) - mean*mean;
    float a = g0[tid] * rsqrtf(var + EPSV);
    aAl[tid] = a;
    aBl[tid] = fmaf(-mean, a, bt0[tid]);
  }
  __syncthreads();
  const int wid = tid>>6, lane = tid&63;
  const int q = lane>>4, nn = lane&15;
  const int p0 = (blockIdx.x*4 + wid) * 32;
  float a_[2][8], b_[2][8];
  #pragma unroll
  for (int kh=0;kh<2;kh++)
    #pragma unroll
    for (int j=0;j<8;j++){
      a_[kh][j] = aAl[kh*32 + q*8 + j];
      b_[kh][j] = aBl[kh*32 + q*8 + j];
    }
  short8 Af[4][2];
  #pragma unroll
  for (int mt=0;mt<4;mt++)
    #pragma unroll
    for (int kh=0;kh<2;kh++)
      Af[mt][kh] = *(const short8*)(Wb + (mt*16 + nn)*64 + kh*32 + q*8);
  float bias_[4][4];
  #pragma unroll
  for (int mt=0;mt<4;mt++)
    #pragma unroll
    for (int r=0;r<4;r++) bias_[mt][r] = bias[mt*16 + q*4 + r];
  floatx4 z = {0.f,0.f,0.f,0.f};
  floatx4 acc[4][2];
  #pragma unroll
  for (int mt=0;mt<4;mt++){ acc[mt][0]=z; acc[mt][1]=z; }
  #pragma unroll
  for (int nt=0;nt<2;nt++){
    #pragma unroll
    for (int kh=0;kh<2;kh++){
      short8 raw = *(const short8*)(yin + (size_t)(p0 + nt*16 + nn)*64 + kh*32 + q*8);
      short8 bf;
      #pragma unroll
      for (int j=0;j<8;j++){
        float f = bf2f((ushort)raw[j]);
        f = fmaxf(fmaf(f, a_[kh][j], b_[kh][j]), 0.f);
        bf[j] = (short)f2bf(f);
      }
      #pragma unroll
      for (int mt=0;mt<4;mt++)
        acc[mt][nt] = __builtin_amdgcn_mfma_f32_16x16x32_bf16(Af[mt][kh], bf, acc[mt][nt], 0,0,0);
    }
  }
  #pragma unroll
  for (int nt=0;nt<2;nt++){
    int p = p0 + nt*16 + nn;
    #pragma unroll
    for (int mt=0;mt<4;mt++){
      float v0 = acc[mt][nt][0] + bias_[mt][0];
      float v1 = acc[mt][nt][1] + bias_[mt][1];
      float v2 = acc[mt][nt][2] + bias_[mt][2];
      float v3 = acc[mt][nt][3] + bias_[mt][3];
      uint2 w;
      w.x = (uint32_t)f2bf(v0) | ((uint32_t)f2bf(v1)<<16);
      w.y = (uint32_t)f2bf(v2) | ((uint32_t)f2bf(v3)<<16);
      *(uint2*)(yout + (size_t)p*64 + mt*16 + q*4) = w;
    }
  }
}

// ---------------- conv3 MFMA: 64->128, tile in LDS, fused group-max + L3 stats ----------------
__global__ __launch_bounds__(256) void conv3_mfma(const ushort* __restrict__ yin,
    float* __restrict__ st, const float* __restrict__ g1, const float* __restrict__ bt1,
    const ushort* __restrict__ Wb, const float* __restrict__ bias,
    ushort* __restrict__ rawmax)
{
  __shared__ ushort tile[64*132];   // 64 pos x 128 ch, pitch 132
  __shared__ float aAl[64], aBl[64];
  const int tid = threadIdx.x;
  if (tid < 64){
    float s = st[256+tid] + st[320+tid];
    float qv = st[384+tid] + st[448+tid];
    float mean = s * (1.f/PTOT);
    float var  = qv * (1.f/PTOT) - mean*mean;
    float a = g1[tid] * rsqrtf(var + EPSV);
    aAl[tid] = a;
    aBl[tid] = fmaf(-mean, a, bt1[tid]);
  }
  __syncthreads();
  const int wid = tid>>6, lane = tid&63;
  const int q = lane>>4, nn = lane&15;
  const int p0 = (blockIdx.x*4 + wid) * 16;
  float a_[2][8], b_[2][8];
  #pragma unroll
  for (int kh=0;kh<2;kh++)
    #pragma unroll
    for (int j=0;j<8;j++){
      a_[kh][j] = aAl[kh*32 + q*8 + j];
      b_[kh][j] = aBl[kh*32 + q*8 + j];
    }
  short8 bfr[2];
  #pragma unroll
  for (int kh=0;kh<2;kh++){
    short8 raw = *(const short8*)(yin + (size_t)(p0 + nn)*64 + kh*32 + q*8);
    short8 bf;
    #pragma unroll
    for (int j=0;j<8;j++){
      float f = bf2f((ushort)raw[j]);
      f = fmaxf(fmaf(f, a_[kh][j], b_[kh][j]), 0.f);
      bf[j] = (short)f2bf(f);
    }
    bfr[kh] = bf;
  }
  #pragma unroll 1
  for (int mh=0;mh<2;mh++){
    floatx4 z = {0.f,0.f,0.f,0.f};
    floatx4 acc[4];
    short8 Af[4][2];
    #pragma unroll
    for (int mt=0;mt<4;mt++){
      acc[mt]=z;
      #pragma unroll
      for (int kh=0;kh<2;kh++)
        Af[mt][kh] = *(const short8*)(Wb + ((mh*4+mt)*16 + nn)*64 + kh*32 + q*8);
    }
    #pragma unroll
    for (int kh=0;kh<2;kh++)
      #pragma unroll
      for (int mt=0;mt<4;mt++)
        acc[mt] = __builtin_amdgcn_mfma_f32_16x16x32_bf16(Af[mt][kh], bfr[kh], acc[mt], 0,0,0);
    #pragma unroll
    for (int mt=0;mt<4;mt++){
      int m0 = (mh*4+mt)*16;
      float v0 = acc[mt][0] + bias[m0 + q*4 + 0];
      float v1 = acc[mt][1] + bias[m0 + q*4 + 1];
      float v2 = acc[mt][2] + bias[m0 + q*4 + 2];
      float v3 = acc[mt][3] + bias[m0 + q*4 + 3];
      uint2 w;
      w.x = (uint32_t)f2bf(v0) | ((uint32_t)f2bf(v1)<<16);
      w.y = (uint32_t)f2bf(v2) | ((uint32_t)f2bf(v3)<<16);
      *(uint2*)&tile[(wid*16 + nn)*132 + m0 + q*4] = w;
    }
  }
  __syncthreads();
  const int c = tid >> 1, half = tid & 1;
  float s = 0.f, q2 = 0.f, mx = -1e30f;
  #pragma unroll 4
  for (int it=0; it<32; it++){
    float f = bf2f(tile[(half*32 + it)*132 + c]);
    s += f; q2 = fmaf(f,f,q2); mx = fmaxf(mx, f);
  }
  rawmax[(size_t)(blockIdx.x*2 + half)*128 + c] = f2bf(mx);
  s  += __shfl_xor(s, 1, 64);
  q2 += __shfl_xor(q2, 1, 64);
  if (half==0){
    int rep = blockIdx.x & 7;
    atomicAdd(&st[512  + rep*128 + c], s);
    atomicAdd(&st[1536 + rep*128 + c], q2);
  }
}

// ---------------- finalize: tiled transpose + affine+relu ----------------
__global__ __launch_bounds__(256) void finalize_kernel(const ushort* __restrict__ rawmax,
    const float* __restrict__ st, const float* __restrict__ g2, const float* __restrict__ bt2,
    float* __restrict__ out)
{
  __shared__ float tile[64][65];
  __shared__ float aAl[128], aBl[128];
  const int tid = threadIdx.x;
  if (tid < 128){
    float s=0.f, qv=0.f;
    #pragma unroll
    for (int r=0;r<8;r++){ s += st[512 + r*128 + tid]; qv += st[1536 + r*128 + tid]; }
    float mean = s * (1.f/PTOT);
    float var  = qv * (1.f/PTOT) - mean*mean;
    float a = g2[tid] * rsqrtf(var + EPSV);
    aAl[tid] = a;
    aBl[tid] = fmaf(-mean, a, bt2[tid]);
  }
  __syncthreads();
  const int b  = blockIdx.x >> 4;
  const int ct = (blockIdx.x >> 3) & 1;
  const int stt = blockIdx.x & 7;
  const int c0 = ct*64, s0 = stt*64;
  const int lane = tid & 63, wid = tid >> 6;
  #pragma unroll
  for (int r=0;r<16;r++){
    int sl = r*4 + wid;
    tile[sl][lane] = bf2f(rawmax[((size_t)(b*512 + s0 + sl))*128 + c0 + lane]);
  }
  __syncthreads();
  #pragma unroll
  for (int r=0;r<16;r++){
    int cl = r*4 + wid;
    float a = aAl[c0+cl], bb = aBl[c0+cl];
    out[((size_t)(b*128 + c0 + cl))*512 + s0 + lane] = fmaxf(fmaf(tile[lane][cl], a, bb), 0.f);
  }
}

extern "C" void kernel_launch(void* const* d_in, const int* in_sizes, int n_in,
                              void* d_out, int out_size, void* d_ws, size_t ws_size,
                              hipStream_t stream) {
  const float* xyz = (const float*)d_in[0];
  const float* pts = (const float*)d_in[1];
  const float* w0  = (const float*)d_in[2];
  const float* b0  = (const float*)d_in[3];
  const float* g0  = (const float*)d_in[4];
  const float* bt0 = (const float*)d_in[5];
  const float* w1  = (const float*)d_in[6];
  const float* b1  = (const float*)d_in[7];
  const float* g1  = (const float*)d_in[8];
  const float* bt1 = (const float*)d_in[9];
  const float* w2  = (const float*)d_in[10];
  const float* b2  = (const float*)d_in[11];
  const float* g2  = (const float*)d_in[12];
  const float* bt2 = (const float*)d_in[13];
  float* out = (float*)d_out;
  float* ws  = (float*)d_ws;

  float* nxyz = ws + WS_NEWXYZ;
  float* st   = ws + WS_ST;
  ushort* w0r = (ushort*)(ws + WS_W0R);
  ushort* w1b = (ushort*)(ws + WS_W1BF);
  ushort* w2b = (ushort*)(ws + WS_W2BF);
  ushort* rawmax = (ushort*)(ws + WS_RAWMAX);
  ushort* pts_tb = (ushort*)(ws + WS_PTS_TB);
  ushort* y1 = (ushort*)(ws + WS_Y1);
  ushort* y2 = (ushort*)(ws + WS_Y2);

  prep_kernel<<<529,256,0,stream>>>(xyz, nxyz, out, pts, pts_tb, w0, w1, w2, w0r, w1b, w2b, st);
  conv1_mfma<<<2048,256,0,stream>>>(xyz, pts_tb, nxyz, w0r, b0, y1);
  stats64_kernel<<<256,256,0,stream>>>(y1, st);
  conv2_mfma<<<2048,256,0,stream>>>(y1, st, g0, bt0, w1b, b1, y2);
  stats64_kernel<<<256,256,0,stream>>>(y2, st + 256);
  conv3_mfma<<<4096,256,0,stream>>>(y2, st, g1, bt1, w2b, b2, rawmax);
  finalize_kernel<<<256,256,0,stream>>>(rawmax, st, g2, bt2, out + NB*3*NS);
}

// Round 14
// 427.382 us; speedup vs baseline: 1.6055x; 1.0066x over previous
//
#include <hip/hip_runtime.h>
#include <hip/hip_bf16.h>
#include <stdint.h>

#define NB 16
#define NPT 2048
#define NS 512
#define NK 32
#define PTOT (NB*NS*NK)   // 262144 positions
#define EPSV 1e-5f

typedef __attribute__((ext_vector_type(8))) short short8;
typedef __attribute__((ext_vector_type(4))) float floatx4;

// ws layout (float indices)
#define WS_NEWXYZ 0            // 24576
// ST: L1 16 reps x (64 sum | 64 sq) @0..2048 | L2 @2048..4096 | L3 sum 8x128@4096 sq@5120 -> 6144
#define WS_ST     24576        // -> 30720
#define WS_W1BF   30720        // 4096 bf16 -> 32768
#define WS_W2BF   32768        // 8192 bf16 -> 36864
#define WS_W0R    36864        // 64x96 bf16 = 3072 fl -> 39936
#define WS_RAWMAX 39936        // 1048576 bf16 -> 564224
#define WS_PTS_TB 564224       // B*N*64 bf16 -> 1612800
#define WS_Y1     1612800      // 8388608 fl -> 10001408
#define WS_Y2     10001408     // -> 18390016  (~74MB)

__device__ __forceinline__ float bf2f(ushort u){ return __uint_as_float((uint32_t)u<<16); }
__device__ __forceinline__ ushort f2bf(float f){
  uint32_t u = __float_as_uint(f);
  return (ushort)((u + 0x7FFFu + ((u>>16)&1u)) >> 16);
}

template<int CTRL>
__device__ __forceinline__ double dppmax64f(double k){
  long long b = __double_as_longlong(k);
  int lo = (int)(uint32_t)b, hi = (int)(b>>32);
  int olo = __builtin_amdgcn_update_dpp(lo, lo, CTRL, 0xF, 0xF, false);
  int ohi = __builtin_amdgcn_update_dpp(hi, hi, CTRL, 0xF, 0xF, false);
  double o = __hiloint2double(ohi, olo);
  return fmax(o, k);
}
__device__ __forceinline__ unsigned long long u64max(unsigned long long a, unsigned long long b){ return a>b?a:b; }

template<int CTRL>
__device__ __forceinline__ float dppaddf(float v){
  int o = __builtin_amdgcn_update_dpp(__float_as_int(v), __float_as_int(v), CTRL, 0xF, 0xF, false);
  return v + __int_as_float(o);
}
// sum within each row16 (valid in all lanes of the row)
__device__ __forceinline__ float rowsum16(float v){
  v = dppaddf<0xB1>(v);
  v = dppaddf<0x4E>(v);
  v = dppaddf<0x124>(v);
  v = dppaddf<0x128>(v);
  return v;
}

// ---------------- prep: fps (0-15, r3 body) + transpose->bf16 (16-527) + wprep (528) ----------------
__global__ __launch_bounds__(256) void prep_kernel(const float* __restrict__ xyz,
    float* __restrict__ nxyz, float* __restrict__ out0,
    const float* __restrict__ pts, ushort* __restrict__ pts_tb,
    const float* __restrict__ w0, const float* __restrict__ w1, const float* __restrict__ w2,
    ushort* __restrict__ w0r, ushort* __restrict__ w1b, ushort* __restrict__ w2b,
    float* __restrict__ st)
{
  __shared__ union {
    struct { float4 lc[NPT]; double warr[2][4]; int sel[NS]; } f;
    float tile[64][65];
  } sm;
  const int blk = blockIdx.x;
  const int tid = threadIdx.x;
  if (blk < 16){
    const int b = blk;
    const float* xb = xyz + (size_t)b*3*NPT;
    float px[8], py[8], pz[8], dist[8];
    uint32_t lo_[8];
    #pragma unroll
    for (int j=0;j<8;j++){
      int n = j*256 + tid;
      float x = xb[n], y = xb[NPT+n], z = xb[2*NPT+n];
      sm.f.lc[n] = make_float4(x,y,z,0.f);
      px[j]=x; py[j]=y; pz[j]=z; dist[j]=1e10f;
      lo_[j] = ~(uint32_t)n;
    }
    if (tid==0) sm.f.sel[0]=0;
    __syncthreads();
    float4 c0 = sm.f.lc[0];
    float cx = c0.x, cy = c0.y, cz = c0.z;
    const int lane = tid & 63, wid = tid >> 6;
    for (int t=1;t<NS;t++){
      double kk[8];
      #pragma unroll
      for (int j=0;j<8;j++){
        float dx = __fsub_rn(px[j], cx);
        float dy = __fsub_rn(py[j], cy);
        float dz = __fsub_rn(pz[j], cz);
        float d  = __fadd_rn(__fadd_rn(__fmul_rn(dx,dx),__fmul_rn(dy,dy)),__fmul_rn(dz,dz));
        float dd = fminf(dist[j], d);
        dist[j] = dd;
        kk[j] = __hiloint2double((int)__float_as_uint(dd), (int)lo_[j]);
      }
      double m0 = fmax(kk[0],kk[1]), m1 = fmax(kk[2],kk[3]);
      double m2 = fmax(kk[4],kk[5]), m3 = fmax(kk[6],kk[7]);
      double best = fmax(fmax(m0,m1), fmax(m2,m3));
      best = dppmax64f<0xB1>(best);    // quad xor1
      best = dppmax64f<0x4E>(best);    // quad xor2
      best = dppmax64f<0x124>(best);   // row_ror:4
      best = dppmax64f<0x128>(best);   // row_ror:8  -> each row16 has its max
      long long bb = __double_as_longlong(best);
      int bl = (int)(uint32_t)bb, bh = (int)(bb>>32);
      unsigned long long k0 = (((unsigned long long)(uint32_t)__builtin_amdgcn_readlane(bh, 0))<<32)  | (uint32_t)__builtin_amdgcn_readlane(bl, 0);
      unsigned long long k1 = (((unsigned long long)(uint32_t)__builtin_amdgcn_readlane(bh, 16))<<32) | (uint32_t)__builtin_amdgcn_readlane(bl, 16);
      unsigned long long k2 = (((unsigned long long)(uint32_t)__builtin_amdgcn_readlane(bh, 32))<<32) | (uint32_t)__builtin_amdgcn_readlane(bl, 32);
      unsigned long long k3 = (((unsigned long long)(uint32_t)__builtin_amdgcn_readlane(bh, 48))<<32) | (uint32_t)__builtin_amdgcn_readlane(bl, 48);
      unsigned long long kw = u64max(u64max(k0,k1), u64max(k2,k3));
      if (lane==0) sm.f.warr[t&1][wid] = __longlong_as_double((long long)kw);
      __syncthreads();
      double w0_ = sm.f.warr[t&1][0], w1_ = sm.f.warr[t&1][1], w2_ = sm.f.warr[t&1][2], w3_ = sm.f.warr[t&1][3];
      double f = fmax(fmax(w0_,w1_), fmax(w2_,w3_));
      int n = (int)(~(uint32_t)__double_as_longlong(f));
      float4 cc = sm.f.lc[n];
      cx = cc.x; cy = cc.y; cz = cc.z;
      if (tid==0) sm.f.sel[t]=n;
    }
    __syncthreads();
    for (int s = tid; s < NS; s += 256){
      int n = sm.f.sel[s];
      float4 cc = sm.f.lc[n];
      float* np_ = nxyz + ((size_t)b*NS + s)*3;
      np_[0]=cc.x; np_[1]=cc.y; np_[2]=cc.z;
      float* ob = out0 + (size_t)b*3*NS + s;
      ob[0]=cc.x; ob[NS]=cc.y; ob[2*NS]=cc.z;
    }
  } else if (blk < 528){
    const int t2 = blk - 16;
    const int b = t2 >> 5;
    const int n0 = (t2 & 31) * 64;
    const int lane = tid & 63;
    const int row4 = tid >> 6;
    const float* src = pts + (size_t)b*64*NPT;
    #pragma unroll
    for (int r=0; r<16; r++){
      int cc = r*4 + row4;
      sm.tile[cc][lane] = src[(size_t)cc*NPT + n0 + lane];
    }
    __syncthreads();
    ushort* dst = pts_tb + ((size_t)b*NPT + n0)*64;
    #pragma unroll
    for (int r=0; r<16; r++){
      int nn = r*4 + row4;
      dst[(size_t)nn*64 + lane] = f2bf(sm.tile[lane][nn]);
    }
  } else {
    for (int i = tid; i < 4096; i += 256) w1b[i] = f2bf(w1[i]);
    for (int i = tid; i < 8192; i += 256) w2b[i] = f2bf(w2[i]);
    for (int i = tid; i < 6144; i += 256) st[i] = 0.f;
    // w0 reorder: col 0-63 = pts weights (w0 col 3..66), 64-66 = xyz weights, 67-95 = 0
    for (int i = tid; i < 6144; i += 256){
      int o = i / 96, k = i - o*96;
      float v = (k < 64) ? w0[o*67 + 3 + k] : ((k < 67) ? w0[o*67 + (k-64)] : 0.f);
      w0r[i] = f2bf(v);
    }
  }
}

// ---------------- conv1 MFMA: ballq + 96->64 + fused L1 stats ----------------
__global__ __launch_bounds__(256) void conv1_mfma(const float* __restrict__ xyz,
    const ushort* __restrict__ pts_tb, const float* __restrict__ nxyz,
    const ushort* __restrict__ w0r, const float* __restrict__ b0,
    ushort* __restrict__ y1, float* __restrict__ st)
{
  __shared__ int gq[4][NK];
  __shared__ float lsum[4][64], lsq[4][64];
  const int tid = threadIdx.x;
  const int wid = tid>>6, lane = tid&63;
  const int q = lane>>4, nn = lane&15;
  const int g = blockIdx.x*4 + wid;          // group 0..8191
  const int b = g >> 9;
  const float* xb = xyz + (size_t)b*3*NPT;
  const float* cgp = nxyz + (size_t)g*3;
  const float cx = cgp[0], cy = cgp[1], cz = cgp[2];
  {
    const float r2 = 0.2f*0.2f;
    int cnt = 0, first = 0;
    for (int ch=0; ch<NPT/64 && cnt<NK; ch++){
      int n = ch*64 + lane;
      float dx = __fsub_rn(cx, xb[n]);
      float dy = __fsub_rn(cy, xb[NPT+n]);
      float dz = __fsub_rn(cz, xb[2*NPT+n]);
      float d  = __fadd_rn(__fadd_rn(__fmul_rn(dx,dx),__fmul_rn(dy,dy)),__fmul_rn(dz,dz));
      bool in = (d <= r2);
      unsigned long long mask = __ballot(in);
      if (mask){
        if (cnt==0) first = ch*64 + (__ffsll((unsigned long long)mask)-1);
        if (in){
          int pos = cnt + __popcll(mask & ((1ull<<lane)-1ull));
          if (pos < NK) gq[wid][pos] = n;
        }
        cnt += __popcll(mask);
      }
    }
    if (cnt < NK && lane >= cnt && lane < NK) gq[wid][lane] = first;
  }
  int n0 = gq[wid][nn], n1 = gq[wid][16+nn];
  float dx0 = xb[n0]-cx, dy0 = xb[NPT+n0]-cy, dz0 = xb[2*NPT+n0]-cz;
  float dx1 = xb[n1]-cx, dy1 = xb[NPT+n1]-cy, dz1 = xb[2*NPT+n1]-cz;
  floatx4 z4 = {0.f,0.f,0.f,0.f};
  floatx4 acc[4][2];
  #pragma unroll
  for (int mt=0;mt<4;mt++){ acc[mt][0]=z4; acc[mt][1]=z4; }
  const ushort* pr0 = pts_tb + ((size_t)b*NPT + n0)*64;
  const ushort* pr1 = pts_tb + ((size_t)b*NPT + n1)*64;
  #pragma unroll
  for (int kh=0; kh<2; kh++){
    short8 B0 = *(const short8*)(pr0 + kh*32 + q*8);
    short8 B1 = *(const short8*)(pr1 + kh*32 + q*8);
    #pragma unroll
    for (int mt=0; mt<4; mt++){
      short8 A = *(const short8*)(w0r + (mt*16+nn)*96 + kh*32 + q*8);
      acc[mt][0] = __builtin_amdgcn_mfma_f32_16x16x32_bf16(A, B0, acc[mt][0], 0,0,0);
      acc[mt][1] = __builtin_amdgcn_mfma_f32_16x16x32_bf16(A, B1, acc[mt][1], 0,0,0);
    }
  }
  {
    short8 B0 = {0,0,0,0,0,0,0,0}, B1 = {0,0,0,0,0,0,0,0};
    if (q==0){
      B0[0]=(short)f2bf(dx0); B0[1]=(short)f2bf(dy0); B0[2]=(short)f2bf(dz0);
      B1[0]=(short)f2bf(dx1); B1[1]=(short)f2bf(dy1); B1[2]=(short)f2bf(dz1);
    }
    #pragma unroll
    for (int mt=0; mt<4; mt++){
      short8 A = *(const short8*)(w0r + (mt*16+nn)*96 + 64 + q*8);
      acc[mt][0] = __builtin_amdgcn_mfma_f32_16x16x32_bf16(A, B0, acc[mt][0], 0,0,0);
      acc[mt][1] = __builtin_amdgcn_mfma_f32_16x16x32_bf16(A, B1, acc[mt][1], 0,0,0);
    }
  }
  float ss[4][4], sq2[4][4];
  #pragma unroll
  for (int mt=0;mt<4;mt++)
    #pragma unroll
    for (int r=0;r<4;r++){ ss[mt][r]=0.f; sq2[mt][r]=0.f; }
  #pragma unroll
  for (int nt=0; nt<2; nt++){
    int p = g*32 + nt*16 + nn;
    #pragma unroll
    for (int mt=0; mt<4; mt++){
      float v0 = acc[mt][nt][0] + b0[mt*16 + q*4 + 0];
      float v1 = acc[mt][nt][1] + b0[mt*16 + q*4 + 1];
      float v2 = acc[mt][nt][2] + b0[mt*16 + q*4 + 2];
      float v3 = acc[mt][nt][3] + b0[mt*16 + q*4 + 3];
      ss[mt][0]+=v0; ss[mt][1]+=v1; ss[mt][2]+=v2; ss[mt][3]+=v3;
      sq2[mt][0]=fmaf(v0,v0,sq2[mt][0]); sq2[mt][1]=fmaf(v1,v1,sq2[mt][1]);
      sq2[mt][2]=fmaf(v2,v2,sq2[mt][2]); sq2[mt][3]=fmaf(v3,v3,sq2[mt][3]);
      uint2 wv;
      wv.x = (uint32_t)f2bf(v0) | ((uint32_t)f2bf(v1)<<16);
      wv.y = (uint32_t)f2bf(v2) | ((uint32_t)f2bf(v3)<<16);
      *(uint2*)(y1 + (size_t)p*64 + mt*16 + q*4) = wv;
    }
  }
  #pragma unroll
  for (int mt=0;mt<4;mt++)
    #pragma unroll
    for (int r=0;r<4;r++){
      float sv = rowsum16(ss[mt][r]);
      float qv = rowsum16(sq2[mt][r]);
      if (nn==0){ lsum[wid][mt*16+q*4+r] = sv; lsq[wid][mt*16+q*4+r] = qv; }
    }
  __syncthreads();
  if (tid < 64){
    float s = lsum[0][tid]+lsum[1][tid]+lsum[2][tid]+lsum[3][tid];
    float q2v = lsq[0][tid]+lsq[1][tid]+lsq[2][tid]+lsq[3][tid];
    int rep = blockIdx.x & 15;
    atomicAdd(&st[rep*128 + tid], s);
    atomicAdd(&st[rep*128 + 64 + tid], q2v);
  }
}

// ---------------- conv2 MFMA: 64->64, affine prologue + fused L2 stats ----------------
__global__ __launch_bounds__(256) void conv2_mfma(const ushort* __restrict__ yin,
    float* __restrict__ st, const float* __restrict__ g0, const float* __restrict__ bt0,
    const ushort* __restrict__ Wb, const float* __restrict__ bias,
    ushort* __restrict__ yout)
{
  __shared__ float aAl[64], aBl[64];
  __shared__ float lsum[4][64], lsq[4][64];
  const int tid = threadIdx.x;
  if (tid < 64){
    float s=0.f, qv=0.f;
    #pragma unroll
    for (int r=0;r<16;r++){ s += st[r*128 + tid]; qv += st[r*128 + 64 + tid]; }
    float mean = s * (1.f/PTOT);
    float var  = qv * (1.f/PTOT) - mean*mean;
    float a = g0[tid] * rsqrtf(var + EPSV);
    aAl[tid] = a;
    aBl[tid] = fmaf(-mean, a, bt0[tid]);
  }
  __syncthreads();
  const int wid = tid>>6, lane = tid&63;
  const int q = lane>>4, nn = lane&15;
  const int p0 = (blockIdx.x*4 + wid) * 32;
  float a_[2][8], b_[2][8];
  #pragma unroll
  for (int kh=0;kh<2;kh++)
    #pragma unroll
    for (int j=0;j<8;j++){
      a_[kh][j] = aAl[kh*32 + q*8 + j];
      b_[kh][j] = aBl[kh*32 + q*8 + j];
    }
  short8 Af[4][2];
  #pragma unroll
  for (int mt=0;mt<4;mt++)
    #pragma unroll
    for (int kh=0;kh<2;kh++)
      Af[mt][kh] = *(const short8*)(Wb + (mt*16 + nn)*64 + kh*32 + q*8);
  float bias_[4][4];
  #pragma unroll
  for (int mt=0;mt<4;mt++)
    #pragma unroll
    for (int r=0;r<4;r++) bias_[mt][r] = bias[mt*16 + q*4 + r];
  floatx4 z = {0.f,0.f,0.f,0.f};
  floatx4 acc[4][2];
  #pragma unroll
  for (int mt=0;mt<4;mt++){ acc[mt][0]=z; acc[mt][1]=z; }
  #pragma unroll
  for (int nt=0;nt<2;nt++){
    #pragma unroll
    for (int kh=0;kh<2;kh++){
      short8 raw = *(const short8*)(yin + (size_t)(p0 + nt*16 + nn)*64 + kh*32 + q*8);
      short8 bf;
      #pragma unroll
      for (int j=0;j<8;j++){
        float f = bf2f((ushort)raw[j]);
        f = fmaxf(fmaf(f, a_[kh][j], b_[kh][j]), 0.f);
        bf[j] = (short)f2bf(f);
      }
      #pragma unroll
      for (int mt=0;mt<4;mt++)
        acc[mt][nt] = __builtin_amdgcn_mfma_f32_16x16x32_bf16(Af[mt][kh], bf, acc[mt][nt], 0,0,0);
    }
  }
  float ss[4][4], sq2[4][4];
  #pragma unroll
  for (int mt=0;mt<4;mt++)
    #pragma unroll
    for (int r=0;r<4;r++){ ss[mt][r]=0.f; sq2[mt][r]=0.f; }
  #pragma unroll
  for (int nt=0;nt<2;nt++){
    int p = p0 + nt*16 + nn;
    #pragma unroll
    for (int mt=0;mt<4;mt++){
      float v0 = acc[mt][nt][0] + bias_[mt][0];
      float v1 = acc[mt][nt][1] + bias_[mt][1];
      float v2 = acc[mt][nt][2] + bias_[mt][2];
      float v3 = acc[mt][nt][3] + bias_[mt][3];
      ss[mt][0]+=v0; ss[mt][1]+=v1; ss[mt][2]+=v2; ss[mt][3]+=v3;
      sq2[mt][0]=fmaf(v0,v0,sq2[mt][0]); sq2[mt][1]=fmaf(v1,v1,sq2[mt][1]);
      sq2[mt][2]=fmaf(v2,v2,sq2[mt][2]); sq2[mt][3]=fmaf(v3,v3,sq2[mt][3]);
      uint2 w;
      w.x = (uint32_t)f2bf(v0) | ((uint32_t)f2bf(v1)<<16);
      w.y = (uint32_t)f2bf(v2) | ((uint32_t)f2bf(v3)<<16);
      *(uint2*)(yout + (size_t)p*64 + mt*16 + q*4) = w;
    }
  }
  #pragma unroll
  for (int mt=0;mt<4;mt++)
    #pragma unroll
    for (int r=0;r<4;r++){
      float sv = rowsum16(ss[mt][r]);
      float qv = rowsum16(sq2[mt][r]);
      if (nn==0){ lsum[wid][mt*16+q*4+r] = sv; lsq[wid][mt*16+q*4+r] = qv; }
    }
  __syncthreads();
  if (tid < 64){
    float s = lsum[0][tid]+lsum[1][tid]+lsum[2][tid]+lsum[3][tid];
    float q2v = lsq[0][tid]+lsq[1][tid]+lsq[2][tid]+lsq[3][tid];
    int rep = blockIdx.x & 15;
    atomicAdd(&st[2048 + rep*128 + tid], s);
    atomicAdd(&st[2048 + rep*128 + 64 + tid], q2v);
  }
}

// ---------------- conv3 MFMA: 64->128, tile in LDS, fused group-max + L3 stats ----------------
__global__ __launch_bounds__(256) void conv3_mfma(const ushort* __restrict__ yin,
    float* __restrict__ st, const float* __restrict__ g1, const float* __restrict__ bt1,
    const ushort* __restrict__ Wb, const float* __restrict__ bias,
    ushort* __restrict__ rawmax)
{
  __shared__ ushort tile[64*132];   // 64 pos x 128 ch, pitch 132
  __shared__ float aAl[64], aBl[64];
  const int tid = threadIdx.x;
  if (tid < 64){
    float s=0.f, qv=0.f;
    #pragma unroll
    for (int r=0;r<16;r++){ s += st[2048 + r*128 + tid]; qv += st[2048 + r*128 + 64 + tid]; }
    float mean = s * (1.f/PTOT);
    float var  = qv * (1.f/PTOT) - mean*mean;
    float a = g1[tid] * rsqrtf(var + EPSV);
    aAl[tid] = a;
    aBl[tid] = fmaf(-mean, a, bt1[tid]);
  }
  __syncthreads();
  const int wid = tid>>6, lane = tid&63;
  const int q = lane>>4, nn = lane&15;
  const int p0 = (blockIdx.x*4 + wid) * 16;
  float a_[2][8], b_[2][8];
  #pragma unroll
  for (int kh=0;kh<2;kh++)
    #pragma unroll
    for (int j=0;j<8;j++){
      a_[kh][j] = aAl[kh*32 + q*8 + j];
      b_[kh][j] = aBl[kh*32 + q*8 + j];
    }
  short8 bfr[2];
  #pragma unroll
  for (int kh=0;kh<2;kh++){
    short8 raw = *(const short8*)(yin + (size_t)(p0 + nn)*64 + kh*32 + q*8);
    short8 bf;
    #pragma unroll
    for (int j=0;j<8;j++){
      float f = bf2f((ushort)raw[j]);
      f = fmaxf(fmaf(f, a_[kh][j], b_[kh][j]), 0.f);
      bf[j] = (short)f2bf(f);
    }
    bfr[kh] = bf;
  }
  #pragma unroll 1
  for (int mh=0;mh<2;mh++){
    floatx4 z = {0.f,0.f,0.f,0.f};
    floatx4 acc[4];
    short8 Af[4][2];
    #pragma unroll
    for (int mt=0;mt<4;mt++){
      acc[mt]=z;
      #pragma unroll
      for (int kh=0;kh<2;kh++)
        Af[mt][kh] = *(const short8*)(Wb + ((mh*4+mt)*16 + nn)*64 + kh*32 + q*8);
    }
    #pragma unroll
    for (int kh=0;kh<2;kh++)
      #pragma unroll
      for (int mt=0;mt<4;mt++)
        acc[mt] = __builtin_amdgcn_mfma_f32_16x16x32_bf16(Af[mt][kh], bfr[kh], acc[mt], 0,0,0);
    #pragma unroll
    for (int mt=0;mt<4;mt++){
      int m0 = (mh*4+mt)*16;
      float v0 = acc[mt][0] + bias[m0 + q*4 + 0];
      float v1 = acc[mt][1] + bias[m0 + q*4 + 1];
      float v2 = acc[mt][2] + bias[m0 + q*4 + 2];
      float v3 = acc[mt][3] + bias[m0 + q*4 + 3];
      uint2 w;
      w.x = (uint32_t)f2bf(v0) | ((uint32_t)f2bf(v1)<<16);
      w.y = (uint32_t)f2bf(v2) | ((uint32_t)f2bf(v3)<<16);
      *(uint2*)&tile[(wid*16 + nn)*132 + m0 + q*4] = w;
    }
  }
  __syncthreads();
  const int c = tid >> 1, half = tid & 1;
  float s = 0.f, q2 = 0.f, mx = -1e30f;
  #pragma unroll 4
  for (int it=0; it<32; it++){
    float f = bf2f(tile[(half*32 + it)*132 + c]);
    s += f; q2 = fmaf(f,f,q2); mx = fmaxf(mx, f);
  }
  rawmax[(size_t)(blockIdx.x*2 + half)*128 + c] = f2bf(mx);
  s  += __shfl_xor(s, 1, 64);
  q2 += __shfl_xor(q2, 1, 64);
  if (half==0){
    int rep = blockIdx.x & 7;
    atomicAdd(&st[4096 + rep*128 + c], s);
    atomicAdd(&st[5120 + rep*128 + c], q2);
  }
}

// ---------------- finalize: tiled transpose + affine+relu ----------------
__global__ __launch_bounds__(256) void finalize_kernel(const ushort* __restrict__ rawmax,
    const float* __restrict__ st, const float* __restrict__ g2, const float* __restrict__ bt2,
    float* __restrict__ out)
{
  __shared__ float tile[64][65];
  __shared__ float aAl[128], aBl[128];
  const int tid = threadIdx.x;
  if (tid < 128){
    float s=0.f, qv=0.f;
    #pragma unroll
    for (int r=0;r<8;r++){ s += st[4096 + r*128 + tid]; qv += st[5120 + r*128 + tid]; }
    float mean = s * (1.f/PTOT);
    float var  = qv * (1.f/PTOT) - mean*mean;
    float a = g2[tid] * rsqrtf(var + EPSV);
    aAl[tid] = a;
    aBl[tid] = fmaf(-mean, a, bt2[tid]);
  }
  __syncthreads();
  const int b  = blockIdx.x >> 4;
  const int ct = (blockIdx.x >> 3) & 1;
  const int stt = blockIdx.x & 7;
  const int c0 = ct*64, s0 = stt*64;
  const int lane = tid & 63, wid = tid >> 6;
  #pragma unroll
  for (int r=0;r<16;r++){
    int sl = r*4 + wid;
    tile[sl][lane] = bf2f(rawmax[((size_t)(b*512 + s0 + sl))*128 + c0 + lane]);
  }
  __syncthreads();
  #pragma unroll
  for (int r=0;r<16;r++){
    int cl = r*4 + wid;
    float a = aAl[c0+cl], bb = aBl[c0+cl];
    out[((size_t)(b*128 + c0 + cl))*512 + s0 + lane] = fmaxf(fmaf(tile[lane][cl], a, bb), 0.f);
  }
}

extern "C" void kernel_launch(void* const* d_in, const int* in_sizes, int n_in,
                              void* d_out, int out_size, void* d_ws, size_t ws_size,
                              hipStream_t stream) {
  const float* xyz = (const float*)d_in[0];
  const float* pts = (const float*)d_in[1];
  const float* w0  = (const float*)d_in[2];
  const float* b0  = (const float*)d_in[3];
  const float* g0  = (const float*)d_in[4];
  const float* bt0 = (const float*)d_in[5];
  const float* w1  = (const float*)d_in[6];
  const float* b1  = (const float*)d_in[7];
  const float* g1  = (const float*)d_in[8];
  const float* bt1 = (const float*)d_in[9];
  const float* w2  = (const float*)d_in[10];
  const float* b2  = (const float*)d_in[11];
  const float* g2  = (const float*)d_in[12];
  const float* bt2 = (const float*)d_in[13];
  float* out = (float*)d_out;
  float* ws  = (float*)d_ws;

  float* nxyz = ws + WS_NEWXYZ;
  float* st   = ws + WS_ST;
  ushort* w0r = (ushort*)(ws + WS_W0R);
  ushort* w1b = (ushort*)(ws + WS_W1BF);
  ushort* w2b = (ushort*)(ws + WS_W2BF);
  ushort* rawmax = (ushort*)(ws + WS_RAWMAX);
  ushort* pts_tb = (ushort*)(ws + WS_PTS_TB);
  ushort* y1 = (ushort*)(ws + WS_Y1);
  ushort* y2 = (ushort*)(ws + WS_Y2);

  prep_kernel<<<529,256,0,stream>>>(xyz, nxyz, out, pts, pts_tb, w0, w1, w2, w0r, w1b, w2b, st);
  conv1_mfma<<<2048,256,0,stream>>>(xyz, pts_tb, nxyz, w0r, b0, y1, st);
  conv2_mfma<<<2048,256,0,stream>>>(y1, st, g0, bt0, w1b, b1, y2);
  conv3_mfma<<<4096,256,0,stream>>>(y2, st, g1, bt1, w2b, b2, rawmax);
  finalize_kernel<<<256,256,0,stream>>>(rawmax, st, g2, bt2, out + NB*3*NS);
}

// Round 15
// 416.097 us; speedup vs baseline: 1.6490x; 1.0271x over previous
//
#include <hip/hip_runtime.h>
#include <hip/hip_bf16.h>
#include <stdint.h>

#define NB 16
#define NPT 2048
#define NS 512
#define NK 32
#define PTOT (NB*NS*NK)   // 262144 positions
#define EPSV 1e-5f

typedef __attribute__((ext_vector_type(8))) short short8;
typedef __attribute__((ext_vector_type(4))) float floatx4;

// ws layout (float indices)
#define WS_NEWXYZ 0            // 24576
// ST: L1 16 reps x (64 sum | 64 sq) @0..2048 | L2 @2048..4096 | L3 sum 8x128@4096 sq@5120 -> 6144
#define WS_ST     24576        // -> 30720
#define WS_W1BF   30720        // 4096 bf16 -> 32768
#define WS_W2BF   32768        // 8192 bf16 -> 36864
#define WS_W0R    36864        // 64x96 bf16 = 3072 fl -> 39936
#define WS_RAWMAX 39936        // 1048576 bf16 -> 564224
#define WS_PTS_TB 564224       // B*N*64 bf16 -> 1612800
#define WS_Y1     1612800      // 8388608 fl -> 10001408
#define WS_Y2     10001408     // -> 18390016  (~74MB)

__device__ __forceinline__ float bf2f(ushort u){ return __uint_as_float((uint32_t)u<<16); }
__device__ __forceinline__ ushort f2bf(float f){
  uint32_t u = __float_as_uint(f);
  return (ushort)((u + 0x7FFFu + ((u>>16)&1u)) >> 16);
}

template<int CTRL>
__device__ __forceinline__ double dppmax64f(double k){
  long long b = __double_as_longlong(k);
  int lo = (int)(uint32_t)b, hi = (int)(b>>32);
  int olo = __builtin_amdgcn_update_dpp(lo, lo, CTRL, 0xF, 0xF, false);
  int ohi = __builtin_amdgcn_update_dpp(hi, hi, CTRL, 0xF, 0xF, false);
  double o = __hiloint2double(ohi, olo);
  return fmax(o, k);
}
__device__ __forceinline__ unsigned long long u64max(unsigned long long a, unsigned long long b){ return a>b?a:b; }

template<int CTRL>
__device__ __forceinline__ float dppaddf(float v){
  int o = __builtin_amdgcn_update_dpp(__float_as_int(v), __float_as_int(v), CTRL, 0xF, 0xF, false);
  return v + __int_as_float(o);
}
// sum within each row16 (valid in all lanes of the row)
__device__ __forceinline__ float rowsum16(float v){
  v = dppaddf<0xB1>(v);
  v = dppaddf<0x4E>(v);
  v = dppaddf<0x124>(v);
  v = dppaddf<0x128>(v);
  return v;
}

// ---------------- prep: fps (0-15, r3 body) + transpose->bf16 (16-527) + wprep (528) ----------------
__global__ __launch_bounds__(256) void prep_kernel(const float* __restrict__ xyz,
    float* __restrict__ nxyz, float* __restrict__ out0,
    const float* __restrict__ pts, ushort* __restrict__ pts_tb,
    const float* __restrict__ w0, const float* __restrict__ w1, const float* __restrict__ w2,
    ushort* __restrict__ w0r, ushort* __restrict__ w1b, ushort* __restrict__ w2b,
    float* __restrict__ st)
{
  __shared__ union {
    struct { float4 lc[NPT]; double warr[2][4]; int sel[NS]; } f;
    float tile[64][65];
  } sm;
  const int blk = blockIdx.x;
  const int tid = threadIdx.x;
  if (blk < 16){
    const int b = blk;
    const float* xb = xyz + (size_t)b*3*NPT;
    float px[8], py[8], pz[8], dist[8];
    uint32_t lo_[8];
    #pragma unroll
    for (int j=0;j<8;j++){
      int n = j*256 + tid;
      float x = xb[n], y = xb[NPT+n], z = xb[2*NPT+n];
      sm.f.lc[n] = make_float4(x,y,z,0.f);
      px[j]=x; py[j]=y; pz[j]=z; dist[j]=1e10f;
      lo_[j] = ~(uint32_t)n;
    }
    if (tid==0) sm.f.sel[0]=0;
    __syncthreads();
    float4 c0 = sm.f.lc[0];
    float cx = c0.x, cy = c0.y, cz = c0.z;
    const int lane = tid & 63, wid = tid >> 6;
    for (int t=1;t<NS;t++){
      double kk[8];
      #pragma unroll
      for (int j=0;j<8;j++){
        float dx = __fsub_rn(px[j], cx);
        float dy = __fsub_rn(py[j], cy);
        float dz = __fsub_rn(pz[j], cz);
        float d  = __fadd_rn(__fadd_rn(__fmul_rn(dx,dx),__fmul_rn(dy,dy)),__fmul_rn(dz,dz));
        float dd = fminf(dist[j], d);
        dist[j] = dd;
        kk[j] = __hiloint2double((int)__float_as_uint(dd), (int)lo_[j]);
      }
      double m0 = fmax(kk[0],kk[1]), m1 = fmax(kk[2],kk[3]);
      double m2 = fmax(kk[4],kk[5]), m3 = fmax(kk[6],kk[7]);
      double best = fmax(fmax(m0,m1), fmax(m2,m3));
      best = dppmax64f<0xB1>(best);    // quad xor1
      best = dppmax64f<0x4E>(best);    // quad xor2
      best = dppmax64f<0x124>(best);   // row_ror:4
      best = dppmax64f<0x128>(best);   // row_ror:8  -> each row16 has its max
      long long bb = __double_as_longlong(best);
      int bl = (int)(uint32_t)bb, bh = (int)(bb>>32);
      unsigned long long k0 = (((unsigned long long)(uint32_t)__builtin_amdgcn_readlane(bh, 0))<<32)  | (uint32_t)__builtin_amdgcn_readlane(bl, 0);
      unsigned long long k1 = (((unsigned long long)(uint32_t)__builtin_amdgcn_readlane(bh, 16))<<32) | (uint32_t)__builtin_amdgcn_readlane(bl, 16);
      unsigned long long k2 = (((unsigned long long)(uint32_t)__builtin_amdgcn_readlane(bh, 32))<<32) | (uint32_t)__builtin_amdgcn_readlane(bl, 32);
      unsigned long long k3 = (((unsigned long long)(uint32_t)__builtin_amdgcn_readlane(bh, 48))<<32) | (uint32_t)__builtin_amdgcn_readlane(bl, 48);
      unsigned long long kw = u64max(u64max(k0,k1), u64max(k2,k3));
      if (lane==0) sm.f.warr[t&1][wid] = __longlong_as_double((long long)kw);
      __syncthreads();
      double w0_ = sm.f.warr[t&1][0], w1_ = sm.f.warr[t&1][1], w2_ = sm.f.warr[t&1][2], w3_ = sm.f.warr[t&1][3];
      double f = fmax(fmax(w0_,w1_), fmax(w2_,w3_));
      int n = (int)(~(uint32_t)__double_as_longlong(f));
      float4 cc = sm.f.lc[n];
      cx = cc.x; cy = cc.y; cz = cc.z;
      if (tid==0) sm.f.sel[t]=n;
    }
    __syncthreads();
    for (int s = tid; s < NS; s += 256){
      int n = sm.f.sel[s];
      float4 cc = sm.f.lc[n];
      float* np_ = nxyz + ((size_t)b*NS + s)*3;
      np_[0]=cc.x; np_[1]=cc.y; np_[2]=cc.z;
      float* ob = out0 + (size_t)b*3*NS + s;
      ob[0]=cc.x; ob[NS]=cc.y; ob[2*NS]=cc.z;
    }
  } else if (blk < 528){
    const int t2 = blk - 16;
    const int b = t2 >> 5;
    const int n0 = (t2 & 31) * 64;
    const int lane = tid & 63;
    const int row4 = tid >> 6;
    const float* src = pts + (size_t)b*64*NPT;
    #pragma unroll
    for (int r=0; r<16; r++){
      int cc = r*4 + row4;
      sm.tile[cc][lane] = src[(size_t)cc*NPT + n0 + lane];
    }
    __syncthreads();
    ushort* dst = pts_tb + ((size_t)b*NPT + n0)*64;
    #pragma unroll
    for (int r=0; r<16; r++){
      int nn = r*4 + row4;
      dst[(size_t)nn*64 + lane] = f2bf(sm.tile[lane][nn]);
    }
  } else {
    for (int i = tid; i < 4096; i += 256) w1b[i] = f2bf(w1[i]);
    for (int i = tid; i < 8192; i += 256) w2b[i] = f2bf(w2[i]);
    for (int i = tid; i < 6144; i += 256) st[i] = 0.f;
    // w0 reorder: col 0-63 = pts weights (w0 col 3..66), 64-66 = xyz weights, 67-95 = 0
    for (int i = tid; i < 6144; i += 256){
      int o = i / 96, k = i - o*96;
      float v = (k < 64) ? w0[o*67 + 3 + k] : ((k < 67) ? w0[o*67 + (k-64)] : 0.f);
      w0r[i] = f2bf(v);
    }
  }
}

// ---------------- conv1 MFMA: two-phase ballq + 96->64 + fused L1 stats ----------------
__global__ __launch_bounds__(256) void conv1_mfma(const float* __restrict__ xyz,
    const ushort* __restrict__ pts_tb, const float* __restrict__ nxyz,
    const ushort* __restrict__ w0r, const float* __restrict__ b0,
    ushort* __restrict__ y1, float* __restrict__ st)
{
  __shared__ int gq[4][NK];
  __shared__ float lsum[4][64], lsq[4][64];
  const int tid = threadIdx.x;
  const int wid = tid>>6, lane = tid&63;
  const int q = lane>>4, nn = lane&15;
  const int g = blockIdx.x*4 + wid;          // group 0..8191
  const int b = g >> 9;
  const float* xb = xyz + (size_t)b*3*NPT;
  const float* cgp = nxyz + (size_t)g*3;
  const float cx = cgp[0], cy = cgp[1], cz = cgp[2];
  {
    const float r2 = 0.2f*0.2f;
    // phase a: branchless in-ball mask (32 independent chunks, loads pipeline freely)
    uint32_t mymask = 0;
    #pragma unroll
    for (int ch=0; ch<NPT/64; ch++){
      int n = ch*64 + lane;
      float dx = __fsub_rn(cx, xb[n]);
      float dy = __fsub_rn(cy, xb[NPT+n]);
      float dz = __fsub_rn(cz, xb[2*NPT+n]);
      float d  = __fadd_rn(__fadd_rn(__fmul_rn(dx,dx),__fmul_rn(dy,dy)),__fmul_rn(dz,dz));
      if (d <= r2) mymask |= (1u<<ch);
    }
    // phase b: load-free collect of first NK by ascending n
    int cnt = 0, first = 0;
    for (int ch=0; ch<NPT/64 && cnt<NK; ch++){
      bool in = (mymask>>ch) & 1u;
      unsigned long long mask = __ballot(in);
      if (mask){
        if (cnt==0) first = ch*64 + (__ffsll((unsigned long long)mask)-1);
        if (in){
          int pos = cnt + __popcll(mask & ((1ull<<lane)-1ull));
          if (pos < NK) gq[wid][pos] = ch*64 + lane;
        }
        cnt += __popcll(mask);
      }
    }
    if (cnt < NK && lane >= cnt && lane < NK) gq[wid][lane] = first;
  }
  int n0 = gq[wid][nn], n1 = gq[wid][16+nn];
  float dx0 = xb[n0]-cx, dy0 = xb[NPT+n0]-cy, dz0 = xb[2*NPT+n0]-cz;
  float dx1 = xb[n1]-cx, dy1 = xb[NPT+n1]-cy, dz1 = xb[2*NPT+n1]-cz;
  floatx4 z4 = {0.f,0.f,0.f,0.f};
  floatx4 acc[4][2];
  #pragma unroll
  for (int mt=0;mt<4;mt++){ acc[mt][0]=z4; acc[mt][1]=z4; }
  const ushort* pr0 = pts_tb + ((size_t)b*NPT + n0)*64;
  const ushort* pr1 = pts_tb + ((size_t)b*NPT + n1)*64;
  #pragma unroll
  for (int kh=0; kh<2; kh++){
    short8 B0 = *(const short8*)(pr0 + kh*32 + q*8);
    short8 B1 = *(const short8*)(pr1 + kh*32 + q*8);
    #pragma unroll
    for (int mt=0; mt<4; mt++){
      short8 A = *(const short8*)(w0r + (mt*16+nn)*96 + kh*32 + q*8);
      acc[mt][0] = __builtin_amdgcn_mfma_f32_16x16x32_bf16(A, B0, acc[mt][0], 0,0,0);
      acc[mt][1] = __builtin_amdgcn_mfma_f32_16x16x32_bf16(A, B1, acc[mt][1], 0,0,0);
    }
  }
  {
    short8 B0 = {0,0,0,0,0,0,0,0}, B1 = {0,0,0,0,0,0,0,0};
    if (q==0){
      B0[0]=(short)f2bf(dx0); B0[1]=(short)f2bf(dy0); B0[2]=(short)f2bf(dz0);
      B1[0]=(short)f2bf(dx1); B1[1]=(short)f2bf(dy1); B1[2]=(short)f2bf(dz1);
    }
    #pragma unroll
    for (int mt=0; mt<4; mt++){
      short8 A = *(const short8*)(w0r + (mt*16+nn)*96 + 64 + q*8);
      acc[mt][0] = __builtin_amdgcn_mfma_f32_16x16x32_bf16(A, B0, acc[mt][0], 0,0,0);
      acc[mt][1] = __builtin_amdgcn_mfma_f32_16x16x32_bf16(A, B1, acc[mt][1], 0,0,0);
    }
  }
  float ss[4][4], sq2[4][4];
  #pragma unroll
  for (int mt=0;mt<4;mt++)
    #pragma unroll
    for (int r=0;r<4;r++){ ss[mt][r]=0.f; sq2[mt][r]=0.f; }
  #pragma unroll
  for (int nt=0; nt<2; nt++){
    int p = g*32 + nt*16 + nn;
    #pragma unroll
    for (int mt=0; mt<4; mt++){
      float v0 = acc[mt][nt][0] + b0[mt*16 + q*4 + 0];
      float v1 = acc[mt][nt][1] + b0[mt*16 + q*4 + 1];
      float v2 = acc[mt][nt][2] + b0[mt*16 + q*4 + 2];
      float v3 = acc[mt][nt][3] + b0[mt*16 + q*4 + 3];
      ss[mt][0]+=v0; ss[mt][1]+=v1; ss[mt][2]+=v2; ss[mt][3]+=v3;
      sq2[mt][0]=fmaf(v0,v0,sq2[mt][0]); sq2[mt][1]=fmaf(v1,v1,sq2[mt][1]);
      sq2[mt][2]=fmaf(v2,v2,sq2[mt][2]); sq2[mt][3]=fmaf(v3,v3,sq2[mt][3]);
      uint2 wv;
      wv.x = (uint32_t)f2bf(v0) | ((uint32_t)f2bf(v1)<<16);
      wv.y = (uint32_t)f2bf(v2) | ((uint32_t)f2bf(v3)<<16);
      *(uint2*)(y1 + (size_t)p*64 + mt*16 + q*4) = wv;
    }
  }
  #pragma unroll
  for (int mt=0;mt<4;mt++)
    #pragma unroll
    for (int r=0;r<4;r++){
      float sv = rowsum16(ss[mt][r]);
      float qv = rowsum16(sq2[mt][r]);
      if (nn==0){ lsum[wid][mt*16+q*4+r] = sv; lsq[wid][mt*16+q*4+r] = qv; }
    }
  __syncthreads();
  if (tid < 64){
    float s = lsum[0][tid]+lsum[1][tid]+lsum[2][tid]+lsum[3][tid];
    float q2v = lsq[0][tid]+lsq[1][tid]+lsq[2][tid]+lsq[3][tid];
    int rep = blockIdx.x & 15;
    atomicAdd(&st[rep*128 + tid], s);
    atomicAdd(&st[rep*128 + 64 + tid], q2v);
  }
}

// ---------------- conv2 MFMA: 64->64, affine prologue + fused L2 stats ----------------
__global__ __launch_bounds__(256) void conv2_mfma(const ushort* __restrict__ yin,
    float* __restrict__ st, const float* __restrict__ g0, const float* __restrict__ bt0,
    const ushort* __restrict__ Wb, const float* __restrict__ bias,
    ushort* __restrict__ yout)
{
  __shared__ float aAl[64], aBl[64];
  __shared__ float lsum[4][64], lsq[4][64];
  const int tid = threadIdx.x;
  if (tid < 64){
    float s=0.f, qv=0.f;
    #pragma unroll
    for (int r=0;r<16;r++){ s += st[r*128 + tid]; qv += st[r*128 + 64 + tid]; }
    float mean = s * (1.f/PTOT);
    float var  = qv * (1.f/PTOT) - mean*mean;
    float a = g0[tid] * rsqrtf(var + EPSV);
    aAl[tid] = a;
    aBl[tid] = fmaf(-mean, a, bt0[tid]);
  }
  __syncthreads();
  const int wid = tid>>6, lane = tid&63;
  const int q = lane>>4, nn = lane&15;
  const int p0 = (blockIdx.x*4 + wid) * 32;
  float a_[2][8], b_[2][8];
  #pragma unroll
  for (int kh=0;kh<2;kh++)
    #pragma unroll
    for (int j=0;j<8;j++){
      a_[kh][j] = aAl[kh*32 + q*8 + j];
      b_[kh][j] = aBl[kh*32 + q*8 + j];
    }
  short8 Af[4][2];
  #pragma unroll
  for (int mt=0;mt<4;mt++)
    #pragma unroll
    for (int kh=0;kh<2;kh++)
      Af[mt][kh] = *(const short8*)(Wb + (mt*16 + nn)*64 + kh*32 + q*8);
  float bias_[4][4];
  #pragma unroll
  for (int mt=0;mt<4;mt++)
    #pragma unroll
    for (int r=0;r<4;r++) bias_[mt][r] = bias[mt*16 + q*4 + r];
  floatx4 z = {0.f,0.f,0.f,0.f};
  floatx4 acc[4][2];
  #pragma unroll
  for (int mt=0;mt<4;mt++){ acc[mt][0]=z; acc[mt][1]=z; }
  #pragma unroll
  for (int nt=0;nt<2;nt++){
    #pragma unroll
    for (int kh=0;kh<2;kh++){
      short8 raw = *(const short8*)(yin + (size_t)(p0 + nt*16 + nn)*64 + kh*32 + q*8);
      short8 bf;
      #pragma unroll
      for (int j=0;j<8;j++){
        float f = bf2f((ushort)raw[j]);
        f = fmaxf(fmaf(f, a_[kh][j], b_[kh][j]), 0.f);
        bf[j] = (short)f2bf(f);
      }
      #pragma unroll
      for (int mt=0;mt<4;mt++)
        acc[mt][nt] = __builtin_amdgcn_mfma_f32_16x16x32_bf16(Af[mt][kh], bf, acc[mt][nt], 0,0,0);
    }
  }
  float ss[4][4], sq2[4][4];
  #pragma unroll
  for (int mt=0;mt<4;mt++)
    #pragma unroll
    for (int r=0;r<4;r++){ ss[mt][r]=0.f; sq2[mt][r]=0.f; }
  #pragma unroll
  for (int nt=0;nt<2;nt++){
    int p = p0 + nt*16 + nn;
    #pragma unroll
    for (int mt=0;mt<4;mt++){
      float v0 = acc[mt][nt][0] + bias_[mt][0];
      float v1 = acc[mt][nt][1] + bias_[mt][1];
      float v2 = acc[mt][nt][2] + bias_[mt][2];
      float v3 = acc[mt][nt][3] + bias_[mt][3];
      ss[mt][0]+=v0; ss[mt][1]+=v1; ss[mt][2]+=v2; ss[mt][3]+=v3;
      sq2[mt][0]=fmaf(v0,v0,sq2[mt][0]); sq2[mt][1]=fmaf(v1,v1,sq2[mt][1]);
      sq2[mt][2]=fmaf(v2,v2,sq2[mt][2]); sq2[mt][3]=fmaf(v3,v3,sq2[mt][3]);
      uint2 w;
      w.x = (uint32_t)f2bf(v0) | ((uint32_t)f2bf(v1)<<16);
      w.y = (uint32_t)f2bf(v2) | ((uint32_t)f2bf(v3)<<16);
      *(uint2*)(yout + (size_t)p*64 + mt*16 + q*4) = w;
    }
  }
  #pragma unroll
  for (int mt=0;mt<4;mt++)
    #pragma unroll
    for (int r=0;r<4;r++){
      float sv = rowsum16(ss[mt][r]);
      float qv = rowsum16(sq2[mt][r]);
      if (nn==0){ lsum[wid][mt*16+q*4+r] = sv; lsq[wid][mt*16+q*4+r] = qv; }
    }
  __syncthreads();
  if (tid < 64){
    float s = lsum[0][tid]+lsum[1][tid]+lsum[2][tid]+lsum[3][tid];
    float q2v = lsq[0][tid]+lsq[1][tid]+lsq[2][tid]+lsq[3][tid];
    int rep = blockIdx.x & 15;
    atomicAdd(&st[2048 + rep*128 + tid], s);
    atomicAdd(&st[2048 + rep*128 + 64 + tid], q2v);
  }
}

// ---------------- conv3 MFMA: 64->128, tile in LDS, fused group-max + L3 stats ----------------
__global__ __launch_bounds__(256) void conv3_mfma(const ushort* __restrict__ yin,
    float* __restrict__ st, const float* __restrict__ g1, const float* __restrict__ bt1,
    const ushort* __restrict__ Wb, const float* __restrict__ bias,
    ushort* __restrict__ rawmax)
{
  __shared__ ushort tile[64*132];   // 64 pos x 128 ch, pitch 132
  __shared__ float aAl[64], aBl[64];
  const int tid = threadIdx.x;
  if (tid < 64){
    float s=0.f, qv=0.f;
    #pragma unroll
    for (int r=0;r<16;r++){ s += st[2048 + r*128 + tid]; qv += st[2048 + r*128 + 64 + tid]; }
    float mean = s * (1.f/PTOT);
    float var  = qv * (1.f/PTOT) - mean*mean;
    float a = g1[tid] * rsqrtf(var + EPSV);
    aAl[tid] = a;
    aBl[tid] = fmaf(-mean, a, bt1[tid]);
  }
  __syncthreads();
  const int wid = tid>>6, lane = tid&63;
  const int q = lane>>4, nn = lane&15;
  const int p0 = (blockIdx.x*4 + wid) * 16;
  float a_[2][8], b_[2][8];
  #pragma unroll
  for (int kh=0;kh<2;kh++)
    #pragma unroll
    for (int j=0;j<8;j++){
      a_[kh][j] = aAl[kh*32 + q*8 + j];
      b_[kh][j] = aBl[kh*32 + q*8 + j];
    }
  short8 bfr[2];
  #pragma unroll
  for (int kh=0;kh<2;kh++){
    short8 raw = *(const short8*)(yin + (size_t)(p0 + nn)*64 + kh*32 + q*8);
    short8 bf;
    #pragma unroll
    for (int j=0;j<8;j++){
      float f = bf2f((ushort)raw[j]);
      f = fmaxf(fmaf(f, a_[kh][j], b_[kh][j]), 0.f);
      bf[j] = (short)f2bf(f);
    }
    bfr[kh] = bf;
  }
  #pragma unroll 1
  for (int mh=0;mh<2;mh++){
    floatx4 z = {0.f,0.f,0.f,0.f};
    floatx4 acc[4];
    short8 Af[4][2];
    #pragma unroll
    for (int mt=0;mt<4;mt++){
      acc[mt]=z;
      #pragma unroll
      for (int kh=0;kh<2;kh++)
        Af[mt][kh] = *(const short8*)(Wb + ((mh*4+mt)*16 + nn)*64 + kh*32 + q*8);
    }
    #pragma unroll
    for (int kh=0;kh<2;kh++)
      #pragma unroll
      for (int mt=0;mt<4;mt++)
        acc[mt] = __builtin_amdgcn_mfma_f32_16x16x32_bf16(Af[mt][kh], bfr[kh], acc[mt], 0,0,0);
    #pragma unroll
    for (int mt=0;mt<4;mt++){
      int m0 = (mh*4+mt)*16;
      float v0 = acc[mt][0] + bias[m0 + q*4 + 0];
      float v1 = acc[mt][1] + bias[m0 + q*4 + 1];
      float v2 = acc[mt][2] + bias[m0 + q*4 + 2];
      float v3 = acc[mt][3] + bias[m0 + q*4 + 3];
      uint2 w;
      w.x = (uint32_t)f2bf(v0) | ((uint32_t)f2bf(v1)<<16);
      w.y = (uint32_t)f2bf(v2) | ((uint32_t)f2bf(v3)<<16);
      *(uint2*)&tile[(wid*16 + nn)*132 + m0 + q*4] = w;
    }
  }
  __syncthreads();
  const int c = tid >> 1, half = tid & 1;
  float s = 0.f, q2 = 0.f, mx = -1e30f;
  #pragma unroll 4
  for (int it=0; it<32; it++){
    float f = bf2f(tile[(half*32 + it)*132 + c]);
    s += f; q2 = fmaf(f,f,q2); mx = fmaxf(mx, f);
  }
  rawmax[(size_t)(blockIdx.x*2 + half)*128 + c] = f2bf(mx);
  s  += __shfl_xor(s, 1, 64);
  q2 += __shfl_xor(q2, 1, 64);
  if (half==0){
    int rep = blockIdx.x & 7;
    atomicAdd(&st[4096 + rep*128 + c], s);
    atomicAdd(&st[5120 + rep*128 + c], q2);
  }
}

// ---------------- finalize: tiled transpose + affine+relu ----------------
__global__ __launch_bounds__(256) void finalize_kernel(const ushort* __restrict__ rawmax,
    const float* __restrict__ st, const float* __restrict__ g2, const float* __restrict__ bt2,
    float* __restrict__ out)
{
  __shared__ float tile[64][65];
  __shared__ float aAl[128], aBl[128];
  const int tid = threadIdx.x;
  if (tid < 128){
    float s=0.f, qv=0.f;
    #pragma unroll
    for (int r=0;r<8;r++){ s += st[4096 + r*128 + tid]; qv += st[5120 + r*128 + tid]; }
    float mean = s * (1.f/PTOT);
    float var  = qv * (1.f/PTOT) - mean*mean;
    float a = g2[tid] * rsqrtf(var + EPSV);
    aAl[tid] = a;
    aBl[tid] = fmaf(-mean, a, bt2[tid]);
  }
  __syncthreads();
  const int b  = blockIdx.x >> 4;
  const int ct = (blockIdx.x >> 3) & 1;
  const int stt = blockIdx.x & 7;
  const int c0 = ct*64, s0 = stt*64;
  const int lane = tid & 63, wid = tid >> 6;
  #pragma unroll
  for (int r=0;r<16;r++){
    int sl = r*4 + wid;
    tile[sl][lane] = bf2f(rawmax[((size_t)(b*512 + s0 + sl))*128 + c0 + lane]);
  }
  __syncthreads();
  #pragma unroll
  for (int r=0;r<16;r++){
    int cl = r*4 + wid;
    float a = aAl[c0+cl], bb = aBl[c0+cl];
    out[((size_t)(b*128 + c0 + cl))*512 + s0 + lane] = fmaxf(fmaf(tile[lane][cl], a, bb), 0.f);
  }
}

extern "C" void kernel_launch(void* const* d_in, const int* in_sizes, int n_in,
                              void* d_out, int out_size, void* d_ws, size_t ws_size,
                              hipStream_t stream) {
  const float* xyz = (const float*)d_in[0];
  const float* pts = (const float*)d_in[1];
  const float* w0  = (const float*)d_in[2];
  const float* b0  = (const float*)d_in[3];
  const float* g0  = (const float*)d_in[4];
  const float* bt0 = (const float*)d_in[5];
  const float* w1  = (const float*)d_in[6];
  const float* b1  = (const float*)d_in[7];
  const float* g1  = (const float*)d_in[8];
  const float* bt1 = (const float*)d_in[9];
  const float* w2  = (const float*)d_in[10];
  const float* b2  = (const float*)d_in[11];
  const float* g2  = (const float*)d_in[12];
  const float* bt2 = (const float*)d_in[13];
  float* out = (float*)d_out;
  float* ws  = (float*)d_ws;

  float* nxyz = ws + WS_NEWXYZ;
  float* st   = ws + WS_ST;
  ushort* w0r = (ushort*)(ws + WS_W0R);
  ushort* w1b = (ushort*)(ws + WS_W1BF);
  ushort* w2b = (ushort*)(ws + WS_W2BF);
  ushort* rawmax = (ushort*)(ws + WS_RAWMAX);
  ushort* pts_tb = (ushort*)(ws + WS_PTS_TB);
  ushort* y1 = (ushort*)(ws + WS_Y1);
  ushort* y2 = (ushort*)(ws + WS_Y2);

  prep_kernel<<<529,256,0,stream>>>(xyz, nxyz, out, pts, pts_tb, w0, w1, w2, w0r, w1b, w2b, st);
  conv1_mfma<<<2048,256,0,stream>>>(xyz, pts_tb, nxyz, w0r, b0, y1, st);
  conv2_mfma<<<2048,256,0,stream>>>(y1, st, g0, bt0, w1b, b1, y2);
  conv3_mfma<<<4096,256,0,stream>>>(y2, st, g1, bt1, w2b, b2, rawmax);
  finalize_kernel<<<256,256,0,stream>>>(rawmax, st, g2, bt2, out + NB*3*NS);
}